// Round 13
// baseline (1462.310 us; speedup 1.0000x reference)
//
#include <hip/hip_runtime.h>
#include <cstdint>
#include <cmath>

#define B_ 64
#define S_ 256
#define IN_ 32
#define D_ 512
#define H_ 8
#define L_ 2
#define DFF_ 2048
#define C_ 16
#define DH_ 64
#define NTOK (B_*S_)   // 16384
#define HALF_ 8192

typedef __attribute__((ext_vector_type(8))) short bf16x8;
typedef __attribute__((ext_vector_type(4))) float f32x4;
typedef __attribute__((ext_vector_type(8))) ushort ushortx8;

__device__ __forceinline__ ushort bf16_rn(float x) {
    union { float f; uint32_t u; } v; v.f = x;
    uint32_t r = v.u + 0x7fffu + ((v.u >> 16) & 1u);
    return (ushort)(r >> 16);
}
__device__ __forceinline__ float bf16_f32(ushort h) {
    union { uint32_t u; float f; } v; v.u = ((uint32_t)h) << 16;
    return v.f;
}

#define GLDS(gp, lp) __builtin_amdgcn_global_load_lds( \
    (const __attribute__((address_space(1))) void*)(gp), \
    (__attribute__((address_space(3))) void*)(lp), 16, 0, 0)

// XCD-chunk bijective swizzle (nwg % 8 == 0 for all users).
__device__ __forceinline__ int xcd_swz(int lid, int nwg) {
    return (lid & 7) * (nwg >> 3) + (lid >> 3);
}

// ---------------------------------------------------------------------------
// Merged bf16x3 GEMM (128x128), T3-minimum 2-phase schedule (guide §5.5):
//   prologue: stage(0); vmcnt(0); barrier
//   loop:     stage(t+1) | ds_read(t) | lgkm(0) | 48 MFMA | vmcnt(0) | barrier
// ONE barrier per K-tile; the stage gets the full read+MFMA span to land.
// MODE: 0 = f32 out, 2 = split hi/lo out, 3 = split + ReLU.
// ---------------------------------------------------------------------------
template<int MODE>
__global__ __launch_bounds__(256)
void gemm3(const ushort* __restrict__ Ahi, const ushort* __restrict__ Alo,
           const ushort* __restrict__ Bhi, const ushort* __restrict__ Blo,
           const float* __restrict__ bias,
           float* __restrict__ Cf, ushort* __restrict__ Chi, ushort* __restrict__ Clo,
           int M, int N, int K)
{
    __shared__ __align__(16) ushort Als[2][2][128*32];
    __shared__ __align__(16) ushort Bls[2][2][128*32];
    const int tid  = threadIdx.x;
    const int wave = tid >> 6, lane = tid & 63;
    const int gx = gridDim.x;
    const int nwg = gx * gridDim.y;
    const int lid = blockIdx.y * gx + blockIdx.x;
    const int xcd = lid & 7, l = lid >> 3;
    const int nl  = nwg >> 3;
    const int GN  = (gx <= 8) ? gx : ((gx == 16) ? 8 : 6);
    const int cm  = nl / gx;
    const int seg = l / (cm * GN);
    const int r   = l - seg * (cm * GN);
    const int m0 = (xcd * cm + r / GN) << 7;
    const int n0 = (seg * GN + r % GN) << 7;
    const int wr = wave >> 1, wc = wave & 1;

    const ushort* Ah = Ahi + (size_t)m0 * K;
    const ushort* Al = Alo + (size_t)m0 * K;
    const ushort* Bh = Bhi + (size_t)n0 * K;
    const ushort* Bl = Blo + (size_t)n0 * K;

    const int KT = K >> 5;

    f32x4 acc[4][4];
    #pragma unroll
    for (int m = 0; m < 4; ++m)
        #pragma unroll
        for (int n = 0; n < 4; ++n)
            acc[m][n] = (f32x4){0.f, 0.f, 0.f, 0.f};

    auto stage = [&](int buf, int kk) {
        #pragma unroll
        for (int i = 0; i < 2; ++i) {
            const int rbase = wave * 32 + i * 16;
            const int row   = rbase + (lane >> 2);
            const int slot  = (lane & 3) ^ ((row >> 1) & 3);
            GLDS(Ah + (size_t)row * K + kk + slot * 8, &Als[buf][0][rbase * 32]);
            GLDS(Al + (size_t)row * K + kk + slot * 8, &Als[buf][1][rbase * 32]);
            GLDS(Bh + (size_t)row * K + kk + slot * 8, &Bls[buf][0][rbase * 32]);
            GLDS(Bl + (size_t)row * K + kk + slot * 8, &Bls[buf][1][rbase * 32]);
        }
    };

    // prologue: tile 0 staged and confirmed
    stage(0, 0);
    asm volatile("s_waitcnt vmcnt(0)" ::: "memory");
    __builtin_amdgcn_sched_barrier(0);
    __builtin_amdgcn_s_barrier();

    for (int t = 0; t < KT; ++t) {
        const int buf = t & 1;
        const bool more = (t + 1 < KT);
        if (more) stage(buf ^ 1, (t + 1) << 5);   // loads fly across the phase

        const int chunk = lane >> 4;
        bf16x8 afh[4], afl[4], bfh[4], bfl[4];
        #pragma unroll
        for (int m = 0; m < 4; ++m) {
            const int row = wr * 64 + m * 16 + (lane & 15);
            const int sl  = chunk ^ ((row >> 1) & 3);
            afh[m] = *(const bf16x8*)(&Als[buf][0][row * 32 + sl * 8]);
            afl[m] = *(const bf16x8*)(&Als[buf][1][row * 32 + sl * 8]);
        }
        #pragma unroll
        for (int n = 0; n < 4; ++n) {
            const int row = wc * 64 + n * 16 + (lane & 15);
            const int sl  = chunk ^ ((row >> 1) & 3);
            bfh[n] = *(const bf16x8*)(&Bls[buf][0][row * 32 + sl * 8]);
            bfl[n] = *(const bf16x8*)(&Bls[buf][1][row * 32 + sl * 8]);
        }
        asm volatile("s_waitcnt lgkmcnt(0)" ::: "memory");
        __builtin_amdgcn_sched_barrier(0);
        #pragma unroll
        for (int m = 0; m < 4; ++m)
            #pragma unroll
            for (int n = 0; n < 4; ++n) {
                acc[m][n] = __builtin_amdgcn_mfma_f32_16x16x32_bf16(afh[m], bfh[n], acc[m][n], 0, 0, 0);
                acc[m][n] = __builtin_amdgcn_mfma_f32_16x16x32_bf16(afh[m], bfl[n], acc[m][n], 0, 0, 0);
                acc[m][n] = __builtin_amdgcn_mfma_f32_16x16x32_bf16(afl[m], bfh[n], acc[m][n], 0, 0, 0);
            }
        if (more) { asm volatile("s_waitcnt vmcnt(0)" ::: "memory"); }
        __builtin_amdgcn_sched_barrier(0);
        __builtin_amdgcn_s_barrier();             // reads done + next tile ready
    }

    const int col_l = lane & 15;
    float bv[4];
    #pragma unroll
    for (int n = 0; n < 4; ++n) bv[n] = bias[n0 + wc * 64 + n * 16 + col_l];
    #pragma unroll
    for (int m = 0; m < 4; ++m) {
        #pragma unroll
        for (int j = 0; j < 4; ++j) {
            const size_t grow = (size_t)(m0 + wr * 64 + m * 16 + (lane >> 4) * 4 + j);
            #pragma unroll
            for (int n = 0; n < 4; ++n) {
                float x = acc[m][n][j] + bv[n];
                if (MODE & 1) x = fmaxf(x, 0.f);
                const size_t gidx = grow * N + (n0 + wc * 64 + n * 16 + col_l);
                if (MODE < 2) {
                    Cf[gidx] = x;
                } else {
                    ushort hb = bf16_rn(x);
                    Chi[gidx] = hb;
                    Clo[gidx] = bf16_rn(x - bf16_f32(hb));
                }
            }
        }
    }
}

// ---------------------------------------------------------------------------
// Dedicated N=128, K=512 bf16x3 GEMM with ReLU+split output (e1/d1 heads).
// Tile 64x128, 4 waves, T3-minimum schedule, 48 KB LDS.
// ---------------------------------------------------------------------------
__global__ __launch_bounds__(256)
void gemm3_n128(const ushort* __restrict__ Ahi, const ushort* __restrict__ Alo,
                const ushort* __restrict__ Bhi, const ushort* __restrict__ Blo,
                const float* __restrict__ bias,
                ushort* __restrict__ Chi, ushort* __restrict__ Clo, int M)
{
    __shared__ __align__(16) ushort Als[2][2][64*32];
    __shared__ __align__(16) ushort Bls[2][2][128*32];
    const int tid = threadIdx.x, wave = tid >> 6, lane = tid & 63;
    const int m0 = xcd_swz(blockIdx.x, gridDim.x) << 6;
    const int K = 512, N = 128;

    const ushort* Ah = Ahi + (size_t)m0 * K;
    const ushort* Al = Alo + (size_t)m0 * K;

    f32x4 acc[4][2];
    #pragma unroll
    for (int m = 0; m < 4; ++m)
        #pragma unroll
        for (int n = 0; n < 2; ++n)
            acc[m][n] = (f32x4){0.f, 0.f, 0.f, 0.f};

    auto stage = [&](int buf, int kk) {
        {
            const int rbase = wave * 16;
            const int row   = rbase + (lane >> 2);
            const int slot  = (lane & 3) ^ ((row >> 1) & 3);
            GLDS(Ah + (size_t)row * K + kk + slot * 8, &Als[buf][0][rbase * 32]);
            GLDS(Al + (size_t)row * K + kk + slot * 8, &Als[buf][1][rbase * 32]);
        }
        #pragma unroll
        for (int i = 0; i < 2; ++i) {
            const int rbase = wave * 32 + i * 16;
            const int row   = rbase + (lane >> 2);
            const int slot  = (lane & 3) ^ ((row >> 1) & 3);
            GLDS(Bhi + (size_t)row * K + kk + slot * 8, &Bls[buf][0][rbase * 32]);
            GLDS(Blo + (size_t)row * K + kk + slot * 8, &Bls[buf][1][rbase * 32]);
        }
    };

    stage(0, 0);
    asm volatile("s_waitcnt vmcnt(0)" ::: "memory");
    __builtin_amdgcn_sched_barrier(0);
    __builtin_amdgcn_s_barrier();

    for (int t = 0; t < 16; ++t) {
        const int buf = t & 1;
        const bool more = (t + 1 < 16);
        if (more) stage(buf ^ 1, (t + 1) << 5);

        const int chunk = lane >> 4;
        bf16x8 afh[4], afl[4], bfh[2], bfl[2];
        #pragma unroll
        for (int m = 0; m < 4; ++m) {
            const int row = m * 16 + (lane & 15);
            const int sl  = chunk ^ ((row >> 1) & 3);
            afh[m] = *(const bf16x8*)(&Als[buf][0][row * 32 + sl * 8]);
            afl[m] = *(const bf16x8*)(&Als[buf][1][row * 32 + sl * 8]);
        }
        #pragma unroll
        for (int n = 0; n < 2; ++n) {
            const int row = wave * 32 + n * 16 + (lane & 15);
            const int sl  = chunk ^ ((row >> 1) & 3);
            bfh[n] = *(const bf16x8*)(&Bls[buf][0][row * 32 + sl * 8]);
            bfl[n] = *(const bf16x8*)(&Bls[buf][1][row * 32 + sl * 8]);
        }
        asm volatile("s_waitcnt lgkmcnt(0)" ::: "memory");
        __builtin_amdgcn_sched_barrier(0);
        #pragma unroll
        for (int m = 0; m < 4; ++m)
            #pragma unroll
            for (int n = 0; n < 2; ++n) {
                acc[m][n] = __builtin_amdgcn_mfma_f32_16x16x32_bf16(afh[m], bfh[n], acc[m][n], 0, 0, 0);
                acc[m][n] = __builtin_amdgcn_mfma_f32_16x16x32_bf16(afh[m], bfl[n], acc[m][n], 0, 0, 0);
                acc[m][n] = __builtin_amdgcn_mfma_f32_16x16x32_bf16(afl[m], bfh[n], acc[m][n], 0, 0, 0);
            }
        if (more) { asm volatile("s_waitcnt vmcnt(0)" ::: "memory"); }
        __builtin_amdgcn_sched_barrier(0);
        __builtin_amdgcn_s_barrier();
    }

    const int col_l = lane & 15;
    float bv[2];
    #pragma unroll
    for (int n = 0; n < 2; ++n) bv[n] = bias[wave * 32 + n * 16 + col_l];
    #pragma unroll
    for (int m = 0; m < 4; ++m) {
        #pragma unroll
        for (int j = 0; j < 4; ++j) {
            const size_t grow = (size_t)(m0 + m * 16 + (lane >> 4) * 4 + j);
            #pragma unroll
            for (int n = 0; n < 2; ++n) {
                float x = fmaxf(acc[m][n][j] + bv[n], 0.f);
                const size_t gidx = grow * N + (wave * 32 + n * 16 + col_l);
                ushort hb = bf16_rn(x);
                Chi[gidx] = hb;
                Clo[gidx] = bf16_rn(x - bf16_f32(hb));
            }
        }
    }
}

// ---------------------------------------------------------------------------
// Fused QK^T + row-softmax (bf16x3) + V-transpose epilogue.
// ---------------------------------------------------------------------------
__global__ __launch_bounds__(256)
void qks_gemm(const ushort* __restrict__ qkvhi, const ushort* __restrict__ qkvlo,
              ushort* __restrict__ Phi, ushort* __restrict__ Plo,
              ushort* __restrict__ VThi, ushort* __restrict__ VTlo)
{
    __shared__ __align__(16) ushort Qls[2][128*64];   // [hi/lo][row*64]
    __shared__ __align__(16) ushort Kls[2][128*64];
    const int tid = threadIdx.x, wave = tid >> 6, lane = tid & 63;
    const int swz = xcd_swz(blockIdx.y * 2 + blockIdx.x, 256);
    const int bh = swz >> 1, qt = swz & 1;
    const int b = bh >> 3, h = bh & 7;

    const ushort* Qh = qkvhi + ((size_t)(b * 256 + qt * 128)) * 1536 + h * 64;
    const ushort* Ql = qkvlo + ((size_t)(b * 256 + qt * 128)) * 1536 + h * 64;
    const ushort* Kh = qkvhi + ((size_t)(b * 256)) * 1536 + 512 + h * 64;
    const ushort* Kl = qkvlo + ((size_t)(b * 256)) * 1536 + 512 + h * 64;

    auto stage128 = [&](const ushort* src, ushort* dst) {
        #pragma unroll
        for (int j = 0; j < 4; ++j) {
            const int rl   = j * 32 + wave * 8 + (lane >> 3);
            const int slot = (lane & 7) ^ (rl & 7);
            GLDS(src + (size_t)rl * 1536 + slot * 8, dst + (j * 32 + wave * 8) * 64);
        }
    };

    f32x4 acc[2][16];
    #pragma unroll
    for (int mi = 0; mi < 2; ++mi)
        #pragma unroll
        for (int nj = 0; nj < 16; ++nj)
            acc[mi][nj] = (f32x4){0.f, 0.f, 0.f, 0.f};

    stage128(Qh, &Qls[0][0]);
    stage128(Ql, &Qls[1][0]);
    stage128(Kh, &Kls[0][0]);
    stage128(Kl, &Kls[1][0]);
    asm volatile("s_waitcnt vmcnt(0)" ::: "memory");
    __builtin_amdgcn_sched_barrier(0);
    __builtin_amdgcn_s_barrier();

    bf16x8 qh[2][2], ql[2][2];
    #pragma unroll
    for (int mi = 0; mi < 2; ++mi)
        #pragma unroll
        for (int ks = 0; ks < 2; ++ks) {
            const int row = wave * 32 + mi * 16 + (lane & 15);
            const int es  = (ks * 4 + (lane >> 4)) ^ (lane & 7);
            qh[mi][ks] = *(const bf16x8*)&Qls[0][row * 64 + es * 8];
            ql[mi][ks] = *(const bf16x8*)&Qls[1][row * 64 + es * 8];
        }

    #pragma unroll
    for (int hk = 0; hk < 2; ++hk) {
        if (hk == 1) {
            __syncthreads();
            stage128(Kh + (size_t)128 * 1536, &Kls[0][0]);
            stage128(Kl + (size_t)128 * 1536, &Kls[1][0]);
            asm volatile("s_waitcnt vmcnt(0)" ::: "memory");
            __builtin_amdgcn_sched_barrier(0);
            __builtin_amdgcn_s_barrier();
        }
        #pragma unroll
        for (int ng = 0; ng < 2; ++ng) {
            bf16x8 kh[4][2], kl[4][2];
            #pragma unroll
            for (int nj = 0; nj < 4; ++nj)
                #pragma unroll
                for (int ks = 0; ks < 2; ++ks) {
                    const int row = (ng * 4 + nj) * 16 + (lane & 15);
                    const int es  = (ks * 4 + (lane >> 4)) ^ (lane & 7);
                    kh[nj][ks] = *(const bf16x8*)&Kls[0][row * 64 + es * 8];
                    kl[nj][ks] = *(const bf16x8*)&Kls[1][row * 64 + es * 8];
                }
            #pragma unroll
            for (int mi = 0; mi < 2; ++mi)
                #pragma unroll
                for (int nj = 0; nj < 4; ++nj) {
                    const int an = hk * 8 + ng * 4 + nj;
                    #pragma unroll
                    for (int ks = 0; ks < 2; ++ks) {
                        acc[mi][an] = __builtin_amdgcn_mfma_f32_16x16x32_bf16(qh[mi][ks], kh[nj][ks], acc[mi][an], 0, 0, 0);
                        acc[mi][an] = __builtin_amdgcn_mfma_f32_16x16x32_bf16(qh[mi][ks], kl[nj][ks], acc[mi][an], 0, 0, 0);
                        acc[mi][an] = __builtin_amdgcn_mfma_f32_16x16x32_bf16(ql[mi][ks], kh[nj][ks], acc[mi][an], 0, 0, 0);
                    }
                }
        }
    }

    const int colb = lane & 15;
    #pragma unroll
    for (int mi = 0; mi < 2; ++mi) {
        #pragma unroll
        for (int j = 0; j < 4; ++j) {
            float v[16];
            float mx = -INFINITY;
            #pragma unroll
            for (int nj = 0; nj < 16; ++nj) {
                v[nj] = acc[mi][nj][j] * 0.125f;
                mx = fmaxf(mx, v[nj]);
            }
            #pragma unroll
            for (int d = 1; d < 16; d <<= 1) mx = fmaxf(mx, __shfl_xor(mx, d));
            float sum = 0.f;
            #pragma unroll
            for (int nj = 0; nj < 16; ++nj) {
                v[nj] = expf(v[nj] - mx);
                sum += v[nj];
            }
            #pragma unroll
            for (int d = 1; d < 16; d <<= 1) sum += __shfl_xor(sum, d);
            const float inv = 1.0f / sum;
            const int qrow = qt * 128 + wave * 32 + mi * 16 + (lane >> 4) * 4 + j;
            const size_t base = ((size_t)bh * 256 + qrow) * 256;
            #pragma unroll
            for (int nj = 0; nj < 16; ++nj) {
                float p = v[nj] * inv;
                ushort hb = bf16_rn(p);
                Phi[base + nj * 16 + colb] = hb;
                Plo[base + nj * 16 + colb] = bf16_rn(p - bf16_f32(hb));
            }
        }
    }

    // fused V-transpose: rows [qt*128, +128) of this bh -> VT
    {
        ushort* T = &Qls[0][0];            // 64*144 = 9216 ushorts
        const int TP = 144;
        const ushort* vsrcs[2] = {
            qkvhi + ((size_t)(b * 256 + qt * 128)) * 1536 + 1024 + h * 64,
            qkvlo + ((size_t)(b * 256 + qt * 128)) * 1536 + 1024 + h * 64 };
        ushort* vdsts[2] = { VThi, VTlo };
        #pragma unroll
        for (int pass = 0; pass < 2; ++pass) {
            __syncthreads();
            if (tid < 128) {
                const ushort* p = vsrcs[pass] + (size_t)tid * 1536;
                #pragma unroll
                for (int i = 0; i < 8; ++i) {
                    ushortx8 vv = *(const ushortx8*)(p + i * 8);
                    #pragma unroll
                    for (int j = 0; j < 8; ++j) T[(i * 8 + j) * TP + tid] = vv[j];
                }
            }
            __syncthreads();
            {
                const int dh = tid >> 2;
                const int kseg = (tid & 3) * 32;
                ushort* op = vdsts[pass] + ((size_t)bh * 64 + dh) * 256 + qt * 128 + kseg;
                #pragma unroll
                for (int i = 0; i < 4; ++i) {
                    ushortx8 vv;
                    #pragma unroll
                    for (int j = 0; j < 8; ++j) vv[j] = T[dh * TP + kseg + i * 8 + j];
                    *(ushortx8*)(op + i * 8) = vv;
                }
            }
        }
    }
}

// ---------------------------------------------------------------------------
// Batched PV: O[q][dh] = P[q][:] . V[:, dh] (bf16x3), O written split hi/lo.
// ---------------------------------------------------------------------------
__global__ __launch_bounds__(256)
void pv_gemm(const ushort* __restrict__ Phi, const ushort* __restrict__ Plo,
             const ushort* __restrict__ VThi, const ushort* __restrict__ VTlo,
             ushort* __restrict__ obhi, ushort* __restrict__ oblo, int t0)
{
    __shared__ __align__(16) ushort Als[2][2][128*32];
    __shared__ __align__(16) ushort Bls[2][2][64*32];
    const int tid = threadIdx.x, wave = tid >> 6, lane = tid & 63;
    const int swz = xcd_swz(blockIdx.y * 2 + blockIdx.x, 256);
    const int bh = swz >> 1, qt = swz & 1;
    const ushort* Ah = Phi + ((size_t)bh * 256 + qt * 128) * 256;
    const ushort* Al = Plo + ((size_t)bh * 256 + qt * 128) * 256;
    const ushort* Bh = VThi + (size_t)bh * 64 * 256;
    const ushort* Bl = VTlo + (size_t)bh * 64 * 256;

    f32x4 acc[2][4];
    #pragma unroll
    for (int m = 0; m < 2; ++m)
        #pragma unroll
        for (int n = 0; n < 4; ++n)
            acc[m][n] = (f32x4){0.f, 0.f, 0.f, 0.f};

    auto stage = [&](int buf, int kk) {
        #pragma unroll
        for (int i = 0; i < 2; ++i) {
            const int rbase = wave * 32 + i * 16;
            const int row   = rbase + (lane >> 2);
            const int slot  = (lane & 3) ^ ((row >> 1) & 3);
            GLDS(Ah + (size_t)row * 256 + kk + slot * 8, &Als[buf][0][rbase * 32]);
            GLDS(Al + (size_t)row * 256 + kk + slot * 8, &Als[buf][1][rbase * 32]);
        }
        const int rbase2 = wave * 16;
        const int row2   = rbase2 + (lane >> 2);
        const int slot2  = (lane & 3) ^ ((row2 >> 1) & 3);
        GLDS(Bh + (size_t)row2 * 256 + kk + slot2 * 8, &Bls[buf][0][rbase2 * 32]);
        GLDS(Bl + (size_t)row2 * 256 + kk + slot2 * 8, &Bls[buf][1][rbase2 * 32]);
    };

    stage(0, 0);
    for (int t = 0; t < 8; ++t) {
        const int buf = t & 1;
        __syncthreads();
        if (t < 7) stage(buf ^ 1, (t + 1) << 5);
        const int chunk = lane >> 4;
        bf16x8 afh[2], afl[2], bfh[4], bfl[4];
        #pragma unroll
        for (int m = 0; m < 2; ++m) {
            const int row = wave * 32 + m * 16 + (lane & 15);
            const int sl  = chunk ^ ((row >> 1) & 3);
            afh[m] = *(const bf16x8*)(&Als[buf][0][row * 32 + sl * 8]);
            afl[m] = *(const bf16x8*)(&Als[buf][1][row * 32 + sl * 8]);
        }
        #pragma unroll
        for (int n = 0; n < 4; ++n) {
            const int row = n * 16 + (lane & 15);
            const int sl  = chunk ^ ((row >> 1) & 3);
            bfh[n] = *(const bf16x8*)(&Bls[buf][0][row * 32 + sl * 8]);
            bfl[n] = *(const bf16x8*)(&Bls[buf][1][row * 32 + sl * 8]);
        }
        #pragma unroll
        for (int m = 0; m < 2; ++m)
            #pragma unroll
            for (int n = 0; n < 4; ++n) {
                acc[m][n] = __builtin_amdgcn_mfma_f32_16x16x32_bf16(afh[m], bfh[n], acc[m][n], 0, 0, 0);
                acc[m][n] = __builtin_amdgcn_mfma_f32_16x16x32_bf16(afh[m], bfl[n], acc[m][n], 0, 0, 0);
                acc[m][n] = __builtin_amdgcn_mfma_f32_16x16x32_bf16(afl[m], bfh[n], acc[m][n], 0, 0, 0);
            }
        __syncthreads();
    }

    const int b = bh >> 3, h = bh & 7;
    const int col_l = lane & 15;
    #pragma unroll
    for (int m = 0; m < 2; ++m)
        #pragma unroll
        for (int j = 0; j < 4; ++j) {
            const int q = qt * 128 + wave * 32 + m * 16 + (lane >> 4) * 4 + j;
            const size_t token = (size_t)t0 + (size_t)b * 256 + q;
            #pragma unroll
            for (int n = 0; n < 4; ++n) {
                const int col = h * 64 + n * 16 + col_l;
                float x = acc[m][n][j];
                ushort hb = bf16_rn(x);
                obhi[token * 512 + col] = hb;
                oblo[token * 512 + col] = bf16_rn(x - bf16_f32(hb));
            }
        }
}

// ---------------------------------------------------------------------------
// f32 GEMM (embedding only, K=32) with fused bf16 hi/lo split output.
// ---------------------------------------------------------------------------
__global__ __launch_bounds__(256)
void gemm_f32(const float* __restrict__ A, const float* __restrict__ W,
              const float* __restrict__ bias, float* __restrict__ Cc,
              ushort* __restrict__ Chi, ushort* __restrict__ Clo,
              int M, int N, int K)
{
    __shared__ float As[16][68];
    __shared__ float Bs[16][64];
    const int tid = threadIdx.x;
    const int tx = tid & 15, ty = tid >> 4;
    const int m0 = blockIdx.y << 6, n0 = blockIdx.x << 6;
    const int arow = tid >> 2, ak4 = (tid & 3) << 2;
    const int brow = tid >> 4, bc4 = (tid & 15) << 2;
    float acc[4][4] = {};
    const float* aptr = A + (size_t)(m0 + arow) * K + ak4;
    const float* bptr = W + (size_t)brow * N + n0 + bc4;
    for (int k0 = 0; k0 < K; k0 += 16) {
        float4 av = *(const float4*)(aptr + k0);
        float4 bv = *(const float4*)(bptr + (size_t)k0 * N);
        __syncthreads();
        As[ak4+0][arow] = av.x; As[ak4+1][arow] = av.y;
        As[ak4+2][arow] = av.z; As[ak4+3][arow] = av.w;
        *(float4*)&Bs[brow][bc4] = bv;
        __syncthreads();
        #pragma unroll
        for (int kk = 0; kk < 16; ++kk) {
            float4 a = *(const float4*)&As[kk][ty << 2];
            float4 b = *(const float4*)&Bs[kk][tx << 2];
            float ar[4] = {a.x,a.y,a.z,a.w};
            float br[4] = {b.x,b.y,b.z,b.w};
            #pragma unroll
            for (int i = 0; i < 4; ++i)
                #pragma unroll
                for (int j = 0; j < 4; ++j)
                    acc[i][j] = fmaf(ar[i], br[j], acc[i][j]);
        }
    }
    float4 bb = *(const float4*)(bias + n0 + (tx << 2));
    #pragma unroll
    for (int i = 0; i < 4; ++i) {
        int m = m0 + (ty << 2) + i;
        float o[4];
        o[0] = acc[i][0] + bb.x; o[1] = acc[i][1] + bb.y;
        o[2] = acc[i][2] + bb.z; o[3] = acc[i][3] + bb.w;
        ushort4 hh, ll;
        hh.x = bf16_rn(o[0]); ll.x = bf16_rn(o[0] - bf16_f32(hh.x));
        hh.y = bf16_rn(o[1]); ll.y = bf16_rn(o[1] - bf16_f32(hh.y));
        hh.z = bf16_rn(o[2]); ll.z = bf16_rn(o[2] - bf16_f32(hh.z));
        hh.w = bf16_rn(o[3]); ll.w = bf16_rn(o[3] - bf16_f32(hh.w));
        const size_t base = (size_t)m * N + n0 + (tx << 2);
        *(float4*)(Cc + base) = (float4){o[0],o[1],o[2],o[3]};
        *(ushort4*)(Chi + base) = hh;
        *(ushort4*)(Clo + base) = ll;
    }
}

// ---------------------------------------------------------------------------
// Per-layer weight prep: all 6 transposes + qkv-bias concat in ONE dispatch.
// ---------------------------------------------------------------------------
__global__ __launch_bounds__(256)
void prep_layer(const float* __restrict__ Wq, const float* __restrict__ Wk,
                const float* __restrict__ Wv, const float* __restrict__ Wo,
                const float* __restrict__ W1, const float* __restrict__ W2,
                const float* __restrict__ bq, const float* __restrict__ bk,
                const float* __restrict__ bv,
                ushort* __restrict__ WTQKV_HI, ushort* __restrict__ WTQKV_LO,
                ushort* __restrict__ WTO_HI, ushort* __restrict__ WTO_LO,
                ushort* __restrict__ WT1_HI, ushort* __restrict__ WT1_LO,
                ushort* __restrict__ WT2_HI, ushort* __restrict__ WT2_LO,
                float* __restrict__ biasqkv)
{
    __shared__ float T[64][65];
    const int blk = blockIdx.x;
    const int tid = threadIdx.x;
    if (blk >= 768) {
        int i = (blk - 768) * 256 + tid;
        biasqkv[i] = (i < 512) ? bq[i] : (i < 1024 ? bk[i - 512] : bv[i - 1024]);
        return;
    }
    const float* W; ushort* Thi; ushort* Tlo; int K, N, bx, by;
    if (blk < 192) {
        const int wsel = blk / 64, idx = blk % 64;
        W = (wsel == 0) ? Wq : ((wsel == 1) ? Wk : Wv);
        Thi = WTQKV_HI + (size_t)wsel * 512 * 512;
        Tlo = WTQKV_LO + (size_t)wsel * 512 * 512;
        K = 512; N = 512; bx = idx % 8; by = idx / 8;
    } else if (blk < 256) {
        const int idx = blk - 192;
        W = Wo; Thi = WTO_HI; Tlo = WTO_LO;
        K = 512; N = 512; bx = idx % 8; by = idx / 8;
    } else if (blk < 512) {
        const int idx = blk - 256;
        W = W1; Thi = WT1_HI; Tlo = WT1_LO;
        K = 512; N = 2048; bx = idx % 32; by = idx / 32;
    } else {
        const int idx = blk - 512;
        W = W2; Thi = WT2_HI; Tlo = WT2_LO;
        K = 2048; N = 512; bx = idx % 8; by = idx / 8;
    }
    const int k0 = by << 6, n0 = bx << 6;
    #pragma unroll
    for (int i = 0; i < 16; ++i) {
        int idx = tid + i * 256;
        int kl = idx >> 6, nl = idx & 63;
        T[nl][kl] = W[(size_t)(k0 + kl) * N + n0 + nl];
    }
    __syncthreads();
    #pragma unroll
    for (int i = 0; i < 16; ++i) {
        int idx = tid + i * 256;
        int nl = idx >> 6, kl = idx & 63;
        float x = T[nl][kl];
        ushort hb = bf16_rn(x);
        size_t o = (size_t)(n0 + nl) * K + k0 + kl;
        Thi[o] = hb;
        Tlo[o] = bf16_rn(x - bf16_f32(hb));
    }
}

// ---------------------------------------------------------------------------
// Head-weight prep: e1/e2/d1/d2 transposes in ONE 64-block dispatch.
// ---------------------------------------------------------------------------
__global__ __launch_bounds__(256)
void prep_heads(const float* __restrict__ e1_w, const float* __restrict__ e2_w,
                const float* __restrict__ d1_w, const float* __restrict__ d2_w,
                ushort* __restrict__ E1H, ushort* __restrict__ E1L,
                ushort* __restrict__ E2H, ushort* __restrict__ E2L,
                ushort* __restrict__ D1H, ushort* __restrict__ D1L,
                ushort* __restrict__ D2H, ushort* __restrict__ D2L)
{
    __shared__ float T[64][65];
    const int blk = blockIdx.x, tid = threadIdx.x;
    const int sel = blk >> 4, idx = blk & 15;
    const float* W; ushort* Thi; ushort* Tlo; int K, N, bx, by;
    if (sel == 0)      { W = e1_w; Thi = E1H; Tlo = E1L; K = 512; N = 128; bx = idx % 2; by = idx / 2; }
    else if (sel == 1) { W = e2_w; Thi = E2H; Tlo = E2L; K = 128; N = 512; bx = idx % 8; by = idx / 8; }
    else if (sel == 2) { W = d1_w; Thi = D1H; Tlo = D1L; K = 512; N = 128; bx = idx % 2; by = idx / 2; }
    else               { W = d2_w; Thi = D2H; Tlo = D2L; K = 128; N = 512; bx = idx % 8; by = idx / 8; }
    const int k0 = by << 6, n0 = bx << 6;
    #pragma unroll
    for (int i = 0; i < 16; ++i) {
        int ix = tid + i * 256;
        int kl = ix >> 6, nl = ix & 63;
        T[nl][kl] = W[(size_t)(k0 + kl) * N + n0 + nl];
    }
    __syncthreads();
    #pragma unroll
    for (int i = 0; i < 16; ++i) {
        int ix = tid + i * 256;
        int nl = ix >> 6, kl = ix & 63;
        float x = T[nl][kl];
        ushort hb = bf16_rn(x);
        size_t o = (size_t)(n0 + nl) * K + k0 + kl;
        Thi[o] = hb;
        Tlo[o] = bf16_rn(x - bf16_f32(hb));
    }
}

// ---------------------------------------------------------------------------
// residual + LN: 4 rows per 256-thread block (one wave per row).
// ---------------------------------------------------------------------------
__global__ __launch_bounds__(256)
void ln_res(float* __restrict__ h, const float* __restrict__ t,
            const float* __restrict__ sc, const float* __restrict__ bi,
            ushort* __restrict__ hhi, ushort* __restrict__ hlo)
{
    const int row = blockIdx.x * 4 + (threadIdx.x >> 6);
    const int lane = threadIdx.x & 63;
    const size_t off = (size_t)row * D_ + (size_t)lane * 8;
    float x[8];
    float4 a0 = *(const float4*)(h + off),  a1 = *(const float4*)(h + off + 4);
    float4 b0 = *(const float4*)(t + off),  b1 = *(const float4*)(t + off + 4);
    x[0]=a0.x+b0.x; x[1]=a0.y+b0.y; x[2]=a0.z+b0.z; x[3]=a0.w+b0.w;
    x[4]=a1.x+b1.x; x[5]=a1.y+b1.y; x[6]=a1.z+b1.z; x[7]=a1.w+b1.w;

    float s = 0.f;
    #pragma unroll
    for (int i = 0; i < 8; ++i) s += x[i];
    #pragma unroll
    for (int d = 1; d < 64; d <<= 1) s += __shfl_xor(s, d);
    float mean = s * (1.0f / 512.0f);

    float vsum = 0.f;
    #pragma unroll
    for (int i = 0; i < 8; ++i) { float dx = x[i] - mean; vsum += dx * dx; }
    #pragma unroll
    for (int d = 1; d < 64; d <<= 1) vsum += __shfl_xor(vsum, d);
    float den = sqrtf(vsum * (1.0f / 512.0f) + 1e-5f);

    float4 s0 = *(const float4*)(sc + lane*8), s1 = *(const float4*)(sc + lane*8 + 4);
    float4 c0 = *(const float4*)(bi + lane*8), c1 = *(const float4*)(bi + lane*8 + 4);
    float scv[8] = {s0.x,s0.y,s0.z,s0.w,s1.x,s1.y,s1.z,s1.w};
    float biv[8] = {c0.x,c0.y,c0.z,c0.w,c1.x,c1.y,c1.z,c1.w};
    float out[8];
    ushort hh[8], ll[8];
    #pragma unroll
    for (int i = 0; i < 8; ++i) {
        out[i] = (x[i] - mean) / den * scv[i] + biv[i];
        hh[i] = bf16_rn(out[i]);
        ll[i] = bf16_rn(out[i] - bf16_f32(hh[i]));
    }
    *(float4*)(h + off)     = (float4){out[0],out[1],out[2],out[3]};
    *(float4*)(h + off + 4) = (float4){out[4],out[5],out[6],out[7]};
    *(ushort4*)(hhi + off)     = (ushort4){hh[0],hh[1],hh[2],hh[3]};
    *(ushort4*)(hhi + off + 4) = (ushort4){hh[4],hh[5],hh[6],hh[7]};
    *(ushort4*)(hlo + off)     = (ushort4){ll[0],ll[1],ll[2],ll[3]};
    *(ushort4*)(hlo + off + 4) = (ushort4){ll[4],ll[5],ll[6],ll[7]};
}

// ---------------------------------------------------------------------------
// z -> d_out copy + sq[token] = sum(z^2), fused. 4 rows/block.
// ---------------------------------------------------------------------------
__global__ __launch_bounds__(256)
void zout_sq(const float* __restrict__ z, float* __restrict__ outz,
             float* __restrict__ sq)
{
#pragma clang fp contract(off)
    const int row = blockIdx.x * 4 + (threadIdx.x >> 6);
    const int lane = threadIdx.x & 63;
    const size_t off = (size_t)row * D_ + (size_t)lane * 8;
    const float* p = z + off;
    float4 a0 = *(const float4*)(p), a1 = *(const float4*)(p + 4);
    float vv[8] = {a0.x,a0.y,a0.z,a0.w,a1.x,a1.y,a1.z,a1.w};
    float* op = outz + off;
    #pragma unroll
    for (int i = 0; i < 8; ++i) op[i] = vv[i];
    float s = 0.f;
    #pragma unroll
    for (int i = 0; i < 8; ++i) { float t = vv[i] * vv[i]; s = s + t; }
    #pragma unroll
    for (int d = 1; d < 64; d <<= 1) s += __shfl_xor(s, d);
    if (lane == 0) sq[row] = s;
}

__global__ __launch_bounds__(256)
void gram_kernel(const float* __restrict__ z, float* __restrict__ gram)
{
    __shared__ float Ls[16][68];
    const int s = blockIdx.x;
    const int tid = threadIdx.x;
    const int tx = tid & 15, ty = tid >> 4;
    const int arow = tid >> 2, ak4 = (tid & 3) << 2;
    float acc[4][4] = {};
    const float* zp = z + ((size_t)arow * S_ + s) * D_ + ak4;
    for (int k0 = 0; k0 < D_; k0 += 16) {
        float4 av = *(const float4*)(zp + k0);
        __syncthreads();
        Ls[ak4+0][arow] = av.x; Ls[ak4+1][arow] = av.y;
        Ls[ak4+2][arow] = av.z; Ls[ak4+3][arow] = av.w;
        __syncthreads();
        #pragma unroll
        for (int kk = 0; kk < 16; ++kk) {
            float4 a = *(const float4*)&Ls[kk][ty << 2];
            float4 b = *(const float4*)&Ls[kk][tx << 2];
            float ar[4] = {a.x,a.y,a.z,a.w};
            float br[4] = {b.x,b.y,b.z,b.w};
            #pragma unroll
            for (int i = 0; i < 4; ++i)
                #pragma unroll
                for (int j = 0; j < 4; ++j)
                    acc[i][j] = fmaf(ar[i], br[j], acc[i][j]);
        }
    }
    #pragma unroll
    for (int i = 0; i < 4; ++i) {
        float4 o = {acc[i][0], acc[i][1], acc[i][2], acc[i][3]};
        *(float4*)(gram + ((size_t)s * 64 + (ty<<2) + i) * 64 + (tx<<2)) = o;
    }
}

__global__ __launch_bounds__(64)
void cluster_kernel(const float* __restrict__ gram, const float* __restrict__ sq,
                    const int* __restrict__ y, float* __restrict__ contrib,
                    int* __restrict__ assigned, float* __restrict__ out_assigned_f)
{
#pragma clang fp contract(off)
    __shared__ float G[64][65];
    __shared__ float sqs[64];
    const int s = blockIdx.x, b = threadIdx.x;
    for (int i = b; i < 4096; i += 64)
        G[i >> 6][i & 63] = gram[(size_t)s * 4096 + i];
    sqs[b] = sq[(size_t)b * S_ + s];
    __syncthreads();

    const float sqb = sqs[b];
    float dmin = INFINITY, dsum = 0.f;
    for (int c = 0; c < 64; ++c) {
        float d = sqb + sqs[c] - 2.0f * G[b][c];
        dmin = fminf(dmin, d);
        dsum = dsum + d;
    }
    float Z = 0.f;
    for (int c = 0; c < 64; ++c) {
        float d = sqb + sqs[c] - 2.0f * G[b][c];
        float e = expf(dmin - d);
        G[b][c] = e;
        Z = Z + e;
    }
    for (int c = 0; c < 64; ++c) G[b][c] = G[b][c] / Z;

    int knn[16];
    #pragma unroll
    for (int j = 0; j < 16; ++j) {
        float bp = -1.f; int bi2 = 0;
        for (int c = 0; c < 64; ++c) {
            float pv = G[b][c];
            if (pv > bp) { bp = pv; bi2 = c; }
        }
        knn[j] = bi2;
        G[b][bi2] = -1.f;
    }
    int cmatch = 0;
    #pragma unroll
    for (int j = 0; j < 16; ++j) cmatch += (knn[j] == j) ? 1 : 0;
    int lab[16];
    #pragma unroll
    for (int j = 0; j < 16; ++j) lab[j] = y[knn[j] * S_ + s];
    int bestc = -1, bestcls = 0;
    #pragma unroll
    for (int cls = 0; cls < 16; ++cls) {
        int cc = 0;
        #pragma unroll
        for (int j = 0; j < 16; ++j) cc += (lab[j] == cls) ? 1 : 0;
        if (cc > bestc) { bestc = cc; bestcls = cls; }
    }
    const int oi = s * 64 + b;
    contrib[oi] = dsum * (float)cmatch;
    assigned[oi] = bestcls;
    out_assigned_f[oi] = (float)bestcls;
}

__global__ __launch_bounds__(256)
void finalize_kernel(const float* __restrict__ contrib, const int* __restrict__ assigned,
                     const int* __restrict__ y, float* __restrict__ dout)
{
#pragma clang fp contract(off)
    __shared__ int cm[256];
    __shared__ float red[256];
    const int tid = threadIdx.x;
    cm[tid] = 0;
    float s = 0.f;
    for (int i = tid; i < NTOK; i += 256) s = s + contrib[i];
    red[tid] = s;
    __syncthreads();
    for (int i = tid; i < NTOK; i += 256)
        atomicAdd(&cm[assigned[i] * 16 + y[i]], 1);
    __syncthreads();
    for (int st = 128; st > 0; st >>= 1) {
        if (tid < st) red[tid] = red[tid] + red[tid + st];
        __syncthreads();
    }
    if (tid == 0) {
        dout[0] = red[0];
        float sij = 0.f, sa = 0.f, sb = 0.f;
        for (int i = 0; i < 256; ++i) {
            float mm = (float)cm[i];
            sij = sij + mm * (mm - 1.0f) * 0.5f;
        }
        for (int r = 0; r < 16; ++r) {
            int rs = 0;
            for (int c2 = 0; c2 < 16; ++c2) rs += cm[r * 16 + c2];
            float mm = (float)rs;
            sa = sa + mm * (mm - 1.0f) * 0.5f;
        }
        for (int c2 = 0; c2 < 16; ++c2) {
            int cs = 0;
            for (int r = 0; r < 16; ++r) cs += cm[r * 16 + c2];
            float mm = (float)cs;
            sb = sb + mm * (mm - 1.0f) * 0.5f;
        }
        float n = 16384.0f;
        float expv = sa * sb / (n * (n - 1.0f) * 0.5f);
        float mx = 0.5f * (sa + sb);
        dout[1] = (sij - expv) / (mx - expv);
    }
}

// ---------------------------------------------------------------------------
extern "C" void kernel_launch(void* const* d_in, const int* in_sizes, int n_in,
                              void* d_out, int out_size, void* d_ws, size_t ws_size,
                              hipStream_t stream)
{
    (void)in_sizes; (void)n_in; (void)out_size; (void)ws_size;
    const float* x     = (const float*)d_in[0];
    const float* W_emb = (const float*)d_in[1];
    const float* b_emb = (const float*)d_in[2];
    const float* Wq    = (const float*)d_in[3];
    const float* bq    = (const float*)d_in[4];
    const float* Wk    = (const float*)d_in[5];
    const float* bk    = (const float*)d_in[6];
    const float* Wv    = (const float*)d_in[7];
    const float* bv    = (const float*)d_in[8];
    const float* Wo    = (const float*)d_in[9];
    const float* bo    = (const float*)d_in[10];
    const float* ln1_s = (const float*)d_in[11];
    const float* ln1_b = (const float*)d_in[12];
    const float* W1    = (const float*)d_in[13];
    const float* b1    = (const float*)d_in[14];
    const float* W2    = (const float*)d_in[15];
    const float* b2    = (const float*)d_in[16];
    const float* ln2_s = (const float*)d_in[17];
    const float* ln2_b = (const float*)d_in[18];
    const float* e1_w  = (const float*)d_in[19];
    const float* e1_b  = (const float*)d_in[20];
    const float* e2_w  = (const float*)d_in[21];
    const float* e2_b  = (const float*)d_in[22];
    const float* d1_w  = (const float*)d_in[23];
    const float* d1_b  = (const float*)d_in[24];
    const float* d2_w  = (const float*)d_in[25];
    const float* d2_b  = (const float*)d_in[26];
    const int*   y     = (const int*)d_in[27];

    float* ws = (float*)d_ws;
    float*  h    = ws;                                   // 8388608
    ushort* hhi  = (ushort*)(ws + 8388608);
    ushort* hlo  = (ushort*)(ws + 12582912);
    float*  SCR  = ws + 16777216;                        // 20971520 slots scratch
    ushort* obhi = (ushort*)(ws + 37748736);
    ushort* oblo = (ushort*)(ws + 41943040);
    float*  wt   = ws + 46137344;
    ushort* WTQKV_HI = (ushort*)wt;
    ushort* WTQKV_LO = WTQKV_HI + 786432;
    ushort* WTO_HI   = WTQKV_LO + 786432;
    ushort* WTO_LO   = WTO_HI + 262144;
    ushort* WT1_HI   = WTO_LO + 262144;
    ushort* WT1_LO   = WT1_HI + 1048576;
    ushort* WT2_HI   = WT1_LO + 1048576;
    ushort* WT2_LO   = WT2_HI + 1048576;
    ushort* WE1_HI   = WT2_LO + 1048576;
    ushort* WE1_LO   = WE1_HI + 65536;
    ushort* WE2_HI   = WE1_LO + 65536;
    ushort* WE2_LO   = WE2_HI + 65536;
    ushort* WD1_HI   = WE2_LO + 65536;
    ushort* WD1_LO   = WD1_HI + 65536;
    ushort* WD2_HI   = WD1_LO + 65536;
    ushort* WD2_LO   = WD2_HI + 65536;
    float*  biasqkv  = ws + 49545216;

    // attention-phase overlays
    ushort* Phi_  = (ushort*)SCR;
    ushort* Plo_  = (ushort*)(SCR + 4194304);
    ushort* qkvhi = (ushort*)(SCR + 8388608);
    ushort* qkvlo = (ushort*)(SCR + 11534336);
    ushort* VThi  = (ushort*)(SCR + 14680064);
    ushort* VTlo  = (ushort*)(SCR + 15728640);
    // post-attention / FFN phase:
    float*  Of32  = SCR;
    ushort* f1hi  = (ushort*)SCR;
    ushort* f1lo  = (ushort*)(SCR + 8388608);
    float*  Xhalf = SCR + 16777216;
    // cluster phase:
    ushort* enchi = (ushort*)SCR;
    ushort* enclo = (ushort*)(SCR + 4194304);
    float*  z     = SCR + 8388608;
    float*  gram  = SCR + 16777216;
    float*  sqb_  = SCR + 17825792;
    float*  contrib = SCR + 17842176;
    int*    assigned = (int*)(SCR + 17858560);
    ushort* t1hi = obhi;
    ushort* t1lo = oblo;
    ushort* t2hi = obhi + 2097152;
    ushort* t2lo = oblo + 2097152;
    float*  dout = (float*)d_out;

    dim3 blk(256);
    auto gg = [](int M, int N) { return dim3(N >> 7, M >> 7); };

    prep_heads<<<dim3(64), blk, 0, stream>>>(e1_w, e2_w, d1_w, d2_w,
        WE1_HI, WE1_LO, WE2_HI, WE2_LO, WD1_HI, WD1_LO, WD2_HI, WD2_LO);

    gemm_f32<<<dim3(8, 256), blk, 0, stream>>>(x, W_emb, b_emb, h, hhi, hlo, NTOK, D_, IN_);

    for (int l = 0; l < L_; ++l) {
        prep_layer<<<dim3(774), blk, 0, stream>>>(
            Wq + (size_t)l*D_*D_, Wk + (size_t)l*D_*D_, Wv + (size_t)l*D_*D_,
            Wo + (size_t)l*D_*D_, W1 + (size_t)l*D_*DFF_, W2 + (size_t)l*DFF_*D_,
            bq + l*D_, bk + l*D_, bv + l*D_,
            WTQKV_HI, WTQKV_LO, WTO_HI, WTO_LO, WT1_HI, WT1_LO, WT2_HI, WT2_LO,
            biasqkv);

        for (int qtr = 0; qtr < 4; ++qtr) {
            const size_t hoff = (size_t)qtr * 4096 * 512;
            gemm3<2><<<gg(4096, 1536), blk, 0, stream>>>(
                hhi + hoff, hlo + hoff, WTQKV_HI, WTQKV_LO, biasqkv,
                nullptr, qkvhi, qkvlo, 4096, 1536, 512);
            qks_gemm<<<dim3(2, 128), blk, 0, stream>>>(qkvhi, qkvlo, Phi_, Plo_,
                                                       VThi, VTlo);
            pv_gemm<<<dim3(2, 128), blk, 0, stream>>>(Phi_, Plo_, VThi, VTlo,
                                                      obhi, oblo, qtr * 4096);
        }
        gemm3<0><<<gg(NTOK, 512), blk, 0, stream>>>(
            obhi, oblo, WTO_HI, WTO_LO, bo + l*D_,
            Of32, nullptr, nullptr, NTOK, 512, 512);
        ln_res<<<dim3(NTOK / 4), blk, 0, stream>>>(h, Of32, ln1_s + l*D_, ln1_b + l*D_, hhi, hlo);

        for (int half = 0; half < 2; ++half) {
            const size_t ro = (size_t)half * HALF_ * D_;
            gemm3<3><<<gg(HALF_, DFF_), blk, 0, stream>>>(
                hhi + ro, hlo + ro, WT1_HI, WT1_LO, b1 + l*DFF_,
                nullptr, f1hi, f1lo, HALF_, 2048, 512);
            gemm3<0><<<gg(HALF_, 512), blk, 0, stream>>>(
                f1hi, f1lo, WT2_HI, WT2_LO, b2 + l*D_,
                Xhalf, nullptr, nullptr, HALF_, 512, 2048);
            ln_res<<<dim3(HALF_ / 4), blk, 0, stream>>>(
                h + ro, Xhalf, ln2_s + l*D_, ln2_b + l*D_, hhi + ro, hlo + ro);
        }
    }

    gemm3_n128<<<dim3(256), blk, 0, stream>>>(
        hhi, hlo, WE1_HI, WE1_LO, e1_b, t1hi, t1lo, NTOK);
    gemm3<2><<<gg(NTOK, 512), blk, 0, stream>>>(
        t1hi, t1lo, WE2_HI, WE2_LO, e2_b, nullptr, enchi, enclo, NTOK, 512, 128);
    gemm3_n128<<<dim3(256), blk, 0, stream>>>(
        enchi, enclo, WD1_HI, WD1_LO, d1_b, t2hi, t2lo, NTOK);
    gemm3<0><<<gg(NTOK, 512), blk, 0, stream>>>(
        t2hi, t2lo, WD2_HI, WD2_LO, d2_b, z, nullptr, nullptr, NTOK, 512, 128);

    zout_sq<<<dim3(NTOK / 4), blk, 0, stream>>>(z, dout + 16386, sqb_);
    gram_kernel<<<dim3(S_), blk, 0, stream>>>(z, gram);
    cluster_kernel<<<dim3(S_), dim3(64), 0, stream>>>(gram, sqb_, y, contrib, assigned, dout + 2);
    finalize_kernel<<<dim3(1), blk, 0, stream>>>(contrib, assigned, y, dout);
}

// Round 14
// 1452.146 us; speedup vs baseline: 1.0070x; 1.0070x over previous
//
#include <hip/hip_runtime.h>
#include <cstdint>
#include <cmath>

#define B_ 64
#define S_ 256
#define IN_ 32
#define D_ 512
#define H_ 8
#define L_ 2
#define DFF_ 2048
#define C_ 16
#define DH_ 64
#define NTOK (B_*S_)   // 16384
#define HALF_ 8192

typedef __attribute__((ext_vector_type(8))) short bf16x8;
typedef __attribute__((ext_vector_type(4))) float f32x4;
typedef __attribute__((ext_vector_type(8))) ushort ushortx8;

__device__ __forceinline__ ushort bf16_rn(float x) {
    union { float f; uint32_t u; } v; v.f = x;
    uint32_t r = v.u + 0x7fffu + ((v.u >> 16) & 1u);
    return (ushort)(r >> 16);
}
__device__ __forceinline__ float bf16_f32(ushort h) {
    union { uint32_t u; float f; } v; v.u = ((uint32_t)h) << 16;
    return v.f;
}

#define GLDS(gp, lp) __builtin_amdgcn_global_load_lds( \
    (const __attribute__((address_space(1))) void*)(gp), \
    (__attribute__((address_space(3))) void*)(lp), 16, 0, 0)

// XCD-chunk bijective swizzle (nwg % 8 == 0 for all users).
__device__ __forceinline__ int xcd_swz(int lid, int nwg) {
    return (lid & 7) * (nwg >> 3) + (lid >> 3);
}

// ---------------------------------------------------------------------------
// Merged bf16x3 GEMM (128x128, 2-phase, counted vmcnt) — round-12 schedule
// (session-best). All 4 operand streams staged once per K-tile
// (48 MFMA : 16 ds_read_b128), 64 KB LDS dbuf. XCD mapping: contiguous
// M-chunk per XCD, N split into GN-groups.
// MODE: 0 = f32 out, 2 = split hi/lo out, 3 = split + ReLU.
// ---------------------------------------------------------------------------
template<int MODE>
__global__ __launch_bounds__(256)
void gemm3(const ushort* __restrict__ Ahi, const ushort* __restrict__ Alo,
           const ushort* __restrict__ Bhi, const ushort* __restrict__ Blo,
           const float* __restrict__ bias,
           float* __restrict__ Cf, ushort* __restrict__ Chi, ushort* __restrict__ Clo,
           int M, int N, int K)
{
    __shared__ __align__(16) ushort Als[2][2][128*32];
    __shared__ __align__(16) ushort Bls[2][2][128*32];
    const int tid  = threadIdx.x;
    const int wave = tid >> 6, lane = tid & 63;
    const int gx = gridDim.x;
    const int nwg = gx * gridDim.y;
    const int lid = blockIdx.y * gx + blockIdx.x;
    const int xcd = lid & 7, l = lid >> 3;
    const int nl  = nwg >> 3;
    const int GN  = (gx <= 8) ? gx : ((gx == 16) ? 8 : 6);
    const int cm  = nl / gx;
    const int seg = l / (cm * GN);
    const int r   = l - seg * (cm * GN);
    const int m0 = (xcd * cm + r / GN) << 7;
    const int n0 = (seg * GN + r % GN) << 7;
    const int wr = wave >> 1, wc = wave & 1;

    const ushort* Ah = Ahi + (size_t)m0 * K;
    const ushort* Al = Alo + (size_t)m0 * K;
    const ushort* Bh = Bhi + (size_t)n0 * K;
    const ushort* Bl = Blo + (size_t)n0 * K;

    const int KT = K >> 5;

    f32x4 acc[4][4];
    #pragma unroll
    for (int m = 0; m < 4; ++m)
        #pragma unroll
        for (int n = 0; n < 4; ++n)
            acc[m][n] = (f32x4){0.f, 0.f, 0.f, 0.f};

    auto stage = [&](int buf, int kk) {
        #pragma unroll
        for (int i = 0; i < 2; ++i) {
            const int rbase = wave * 32 + i * 16;
            const int row   = rbase + (lane >> 2);
            const int slot  = (lane & 3) ^ ((row >> 1) & 3);
            GLDS(Ah + (size_t)row * K + kk + slot * 8, &Als[buf][0][rbase * 32]);
            GLDS(Al + (size_t)row * K + kk + slot * 8, &Als[buf][1][rbase * 32]);
            GLDS(Bh + (size_t)row * K + kk + slot * 8, &Bls[buf][0][rbase * 32]);
            GLDS(Bl + (size_t)row * K + kk + slot * 8, &Bls[buf][1][rbase * 32]);
        }
    };

    stage(0, 0);
    for (int t = 0; t < KT; ++t) {
        const int buf = t & 1;
        if (t + 1 < KT) {
            stage(buf ^ 1, (t + 1) << 5);
            asm volatile("s_waitcnt vmcnt(8)" ::: "memory");
        } else {
            asm volatile("s_waitcnt vmcnt(0)" ::: "memory");
        }
        __builtin_amdgcn_sched_barrier(0);
        __builtin_amdgcn_s_barrier();

        const int chunk = lane >> 4;
        bf16x8 afh[4], afl[4], bfh[4], bfl[4];
        #pragma unroll
        for (int m = 0; m < 4; ++m) {
            const int row = wr * 64 + m * 16 + (lane & 15);
            const int sl  = chunk ^ ((row >> 1) & 3);
            afh[m] = *(const bf16x8*)(&Als[buf][0][row * 32 + sl * 8]);
            afl[m] = *(const bf16x8*)(&Als[buf][1][row * 32 + sl * 8]);
        }
        #pragma unroll
        for (int n = 0; n < 4; ++n) {
            const int row = wc * 64 + n * 16 + (lane & 15);
            const int sl  = chunk ^ ((row >> 1) & 3);
            bfh[n] = *(const bf16x8*)(&Bls[buf][0][row * 32 + sl * 8]);
            bfl[n] = *(const bf16x8*)(&Bls[buf][1][row * 32 + sl * 8]);
        }
        #pragma unroll
        for (int m = 0; m < 4; ++m)
            #pragma unroll
            for (int n = 0; n < 4; ++n) {
                acc[m][n] = __builtin_amdgcn_mfma_f32_16x16x32_bf16(afh[m], bfh[n], acc[m][n], 0, 0, 0);
                acc[m][n] = __builtin_amdgcn_mfma_f32_16x16x32_bf16(afh[m], bfl[n], acc[m][n], 0, 0, 0);
                acc[m][n] = __builtin_amdgcn_mfma_f32_16x16x32_bf16(afl[m], bfh[n], acc[m][n], 0, 0, 0);
            }
        __builtin_amdgcn_sched_barrier(0);
        __builtin_amdgcn_s_barrier();
    }

    const int col_l = lane & 15;
    float bv[4];
    #pragma unroll
    for (int n = 0; n < 4; ++n) bv[n] = bias[n0 + wc * 64 + n * 16 + col_l];
    #pragma unroll
    for (int m = 0; m < 4; ++m) {
        #pragma unroll
        for (int j = 0; j < 4; ++j) {
            const size_t grow = (size_t)(m0 + wr * 64 + m * 16 + (lane >> 4) * 4 + j);
            #pragma unroll
            for (int n = 0; n < 4; ++n) {
                float x = acc[m][n][j] + bv[n];
                if (MODE & 1) x = fmaxf(x, 0.f);
                const size_t gidx = grow * N + (n0 + wc * 64 + n * 16 + col_l);
                if (MODE < 2) {
                    Cf[gidx] = x;
                } else {
                    ushort hb = bf16_rn(x);
                    Chi[gidx] = hb;
                    Clo[gidx] = bf16_rn(x - bf16_f32(hb));
                }
            }
        }
    }
}

// ---------------------------------------------------------------------------
// Dedicated N=128, K=512 bf16x3 GEMM with ReLU+split output (e1/d1 heads).
// Round-12 schedule (two-barrier, vmcnt(6)). Tile 64x128, 48 KB LDS.
// ---------------------------------------------------------------------------
__global__ __launch_bounds__(256)
void gemm3_n128(const ushort* __restrict__ Ahi, const ushort* __restrict__ Alo,
                const ushort* __restrict__ Bhi, const ushort* __restrict__ Blo,
                const float* __restrict__ bias,
                ushort* __restrict__ Chi, ushort* __restrict__ Clo, int M)
{
    __shared__ __align__(16) ushort Als[2][2][64*32];
    __shared__ __align__(16) ushort Bls[2][2][128*32];
    const int tid = threadIdx.x, wave = tid >> 6, lane = tid & 63;
    const int m0 = xcd_swz(blockIdx.x, gridDim.x) << 6;
    const int K = 512, N = 128;

    const ushort* Ah = Ahi + (size_t)m0 * K;
    const ushort* Al = Alo + (size_t)m0 * K;

    f32x4 acc[4][2];
    #pragma unroll
    for (int m = 0; m < 4; ++m)
        #pragma unroll
        for (int n = 0; n < 2; ++n)
            acc[m][n] = (f32x4){0.f, 0.f, 0.f, 0.f};

    auto stage = [&](int buf, int kk) {
        {
            const int rbase = wave * 16;
            const int row   = rbase + (lane >> 2);
            const int slot  = (lane & 3) ^ ((row >> 1) & 3);
            GLDS(Ah + (size_t)row * K + kk + slot * 8, &Als[buf][0][rbase * 32]);
            GLDS(Al + (size_t)row * K + kk + slot * 8, &Als[buf][1][rbase * 32]);
        }
        #pragma unroll
        for (int i = 0; i < 2; ++i) {
            const int rbase = wave * 32 + i * 16;
            const int row   = rbase + (lane >> 2);
            const int slot  = (lane & 3) ^ ((row >> 1) & 3);
            GLDS(Bhi + (size_t)row * K + kk + slot * 8, &Bls[buf][0][rbase * 32]);
            GLDS(Blo + (size_t)row * K + kk + slot * 8, &Bls[buf][1][rbase * 32]);
        }
    };

    stage(0, 0);
    for (int t = 0; t < 16; ++t) {
        const int buf = t & 1;
        if (t + 1 < 16) {
            stage(buf ^ 1, (t + 1) << 5);
            asm volatile("s_waitcnt vmcnt(6)" ::: "memory");
        } else {
            asm volatile("s_waitcnt vmcnt(0)" ::: "memory");
        }
        __builtin_amdgcn_sched_barrier(0);
        __builtin_amdgcn_s_barrier();

        const int chunk = lane >> 4;
        bf16x8 afh[4], afl[4], bfh[2], bfl[2];
        #pragma unroll
        for (int m = 0; m < 4; ++m) {
            const int row = m * 16 + (lane & 15);
            const int sl  = chunk ^ ((row >> 1) & 3);
            afh[m] = *(const bf16x8*)(&Als[buf][0][row * 32 + sl * 8]);
            afl[m] = *(const bf16x8*)(&Als[buf][1][row * 32 + sl * 8]);
        }
        #pragma unroll
        for (int n = 0; n < 2; ++n) {
            const int row = wave * 32 + n * 16 + (lane & 15);
            const int sl  = chunk ^ ((row >> 1) & 3);
            bfh[n] = *(const bf16x8*)(&Bls[buf][0][row * 32 + sl * 8]);
            bfl[n] = *(const bf16x8*)(&Bls[buf][1][row * 32 + sl * 8]);
        }
        #pragma unroll
        for (int m = 0; m < 4; ++m)
            #pragma unroll
            for (int n = 0; n < 2; ++n) {
                acc[m][n] = __builtin_amdgcn_mfma_f32_16x16x32_bf16(afh[m], bfh[n], acc[m][n], 0, 0, 0);
                acc[m][n] = __builtin_amdgcn_mfma_f32_16x16x32_bf16(afh[m], bfl[n], acc[m][n], 0, 0, 0);
                acc[m][n] = __builtin_amdgcn_mfma_f32_16x16x32_bf16(afl[m], bfh[n], acc[m][n], 0, 0, 0);
            }
        __builtin_amdgcn_sched_barrier(0);
        __builtin_amdgcn_s_barrier();
    }

    const int col_l = lane & 15;
    float bv[2];
    #pragma unroll
    for (int n = 0; n < 2; ++n) bv[n] = bias[wave * 32 + n * 16 + col_l];
    #pragma unroll
    for (int m = 0; m < 4; ++m) {
        #pragma unroll
        for (int j = 0; j < 4; ++j) {
            const size_t grow = (size_t)(m0 + m * 16 + (lane >> 4) * 4 + j);
            #pragma unroll
            for (int n = 0; n < 2; ++n) {
                float x = fmaxf(acc[m][n][j] + bv[n], 0.f);
                const size_t gidx = grow * N + (wave * 32 + n * 16 + col_l);
                ushort hb = bf16_rn(x);
                Chi[gidx] = hb;
                Clo[gidx] = bf16_rn(x - bf16_f32(hb));
            }
        }
    }
}

// ---------------------------------------------------------------------------
// Fused QK^T + row-softmax (bf16x3) + V-transpose epilogue.
// ---------------------------------------------------------------------------
__global__ __launch_bounds__(256)
void qks_gemm(const ushort* __restrict__ qkvhi, const ushort* __restrict__ qkvlo,
              ushort* __restrict__ Phi, ushort* __restrict__ Plo,
              ushort* __restrict__ VThi, ushort* __restrict__ VTlo)
{
    __shared__ __align__(16) ushort Qls[2][128*64];   // [hi/lo][row*64]
    __shared__ __align__(16) ushort Kls[2][128*64];
    const int tid = threadIdx.x, wave = tid >> 6, lane = tid & 63;
    const int swz = xcd_swz(blockIdx.y * 2 + blockIdx.x, 256);
    const int bh = swz >> 1, qt = swz & 1;
    const int b = bh >> 3, h = bh & 7;

    const ushort* Qh = qkvhi + ((size_t)(b * 256 + qt * 128)) * 1536 + h * 64;
    const ushort* Ql = qkvlo + ((size_t)(b * 256 + qt * 128)) * 1536 + h * 64;
    const ushort* Kh = qkvhi + ((size_t)(b * 256)) * 1536 + 512 + h * 64;
    const ushort* Kl = qkvlo + ((size_t)(b * 256)) * 1536 + 512 + h * 64;

    auto stage128 = [&](const ushort* src, ushort* dst) {
        #pragma unroll
        for (int j = 0; j < 4; ++j) {
            const int rl   = j * 32 + wave * 8 + (lane >> 3);
            const int slot = (lane & 7) ^ (rl & 7);
            GLDS(src + (size_t)rl * 1536 + slot * 8, dst + (j * 32 + wave * 8) * 64);
        }
    };

    f32x4 acc[2][16];
    #pragma unroll
    for (int mi = 0; mi < 2; ++mi)
        #pragma unroll
        for (int nj = 0; nj < 16; ++nj)
            acc[mi][nj] = (f32x4){0.f, 0.f, 0.f, 0.f};

    stage128(Qh, &Qls[0][0]);
    stage128(Ql, &Qls[1][0]);
    stage128(Kh, &Kls[0][0]);
    stage128(Kl, &Kls[1][0]);
    asm volatile("s_waitcnt vmcnt(0)" ::: "memory");
    __builtin_amdgcn_sched_barrier(0);
    __builtin_amdgcn_s_barrier();

    bf16x8 qh[2][2], ql[2][2];
    #pragma unroll
    for (int mi = 0; mi < 2; ++mi)
        #pragma unroll
        for (int ks = 0; ks < 2; ++ks) {
            const int row = wave * 32 + mi * 16 + (lane & 15);
            const int es  = (ks * 4 + (lane >> 4)) ^ (lane & 7);
            qh[mi][ks] = *(const bf16x8*)&Qls[0][row * 64 + es * 8];
            ql[mi][ks] = *(const bf16x8*)&Qls[1][row * 64 + es * 8];
        }

    #pragma unroll
    for (int hk = 0; hk < 2; ++hk) {
        if (hk == 1) {
            __syncthreads();
            stage128(Kh + (size_t)128 * 1536, &Kls[0][0]);
            stage128(Kl + (size_t)128 * 1536, &Kls[1][0]);
            asm volatile("s_waitcnt vmcnt(0)" ::: "memory");
            __builtin_amdgcn_sched_barrier(0);
            __builtin_amdgcn_s_barrier();
        }
        #pragma unroll
        for (int ng = 0; ng < 2; ++ng) {
            bf16x8 kh[4][2], kl[4][2];
            #pragma unroll
            for (int nj = 0; nj < 4; ++nj)
                #pragma unroll
                for (int ks = 0; ks < 2; ++ks) {
                    const int row = (ng * 4 + nj) * 16 + (lane & 15);
                    const int es  = (ks * 4 + (lane >> 4)) ^ (lane & 7);
                    kh[nj][ks] = *(const bf16x8*)&Kls[0][row * 64 + es * 8];
                    kl[nj][ks] = *(const bf16x8*)&Kls[1][row * 64 + es * 8];
                }
            #pragma unroll
            for (int mi = 0; mi < 2; ++mi)
                #pragma unroll
                for (int nj = 0; nj < 4; ++nj) {
                    const int an = hk * 8 + ng * 4 + nj;
                    #pragma unroll
                    for (int ks = 0; ks < 2; ++ks) {
                        acc[mi][an] = __builtin_amdgcn_mfma_f32_16x16x32_bf16(qh[mi][ks], kh[nj][ks], acc[mi][an], 0, 0, 0);
                        acc[mi][an] = __builtin_amdgcn_mfma_f32_16x16x32_bf16(qh[mi][ks], kl[nj][ks], acc[mi][an], 0, 0, 0);
                        acc[mi][an] = __builtin_amdgcn_mfma_f32_16x16x32_bf16(ql[mi][ks], kh[nj][ks], acc[mi][an], 0, 0, 0);
                    }
                }
        }
    }

    const int colb = lane & 15;
    #pragma unroll
    for (int mi = 0; mi < 2; ++mi) {
        #pragma unroll
        for (int j = 0; j < 4; ++j) {
            float v[16];
            float mx = -INFINITY;
            #pragma unroll
            for (int nj = 0; nj < 16; ++nj) {
                v[nj] = acc[mi][nj][j] * 0.125f;
                mx = fmaxf(mx, v[nj]);
            }
            #pragma unroll
            for (int d = 1; d < 16; d <<= 1) mx = fmaxf(mx, __shfl_xor(mx, d));
            float sum = 0.f;
            #pragma unroll
            for (int nj = 0; nj < 16; ++nj) {
                v[nj] = expf(v[nj] - mx);
                sum += v[nj];
            }
            #pragma unroll
            for (int d = 1; d < 16; d <<= 1) sum += __shfl_xor(sum, d);
            const float inv = 1.0f / sum;
            const int qrow = qt * 128 + wave * 32 + mi * 16 + (lane >> 4) * 4 + j;
            const size_t base = ((size_t)bh * 256 + qrow) * 256;
            #pragma unroll
            for (int nj = 0; nj < 16; ++nj) {
                float p = v[nj] * inv;
                ushort hb = bf16_rn(p);
                Phi[base + nj * 16 + colb] = hb;
                Plo[base + nj * 16 + colb] = bf16_rn(p - bf16_f32(hb));
            }
        }
    }

    // fused V-transpose: rows [qt*128, +128) of this bh -> VT
    {
        ushort* T = &Qls[0][0];            // 64*144 = 9216 ushorts
        const int TP = 144;
        const ushort* vsrcs[2] = {
            qkvhi + ((size_t)(b * 256 + qt * 128)) * 1536 + 1024 + h * 64,
            qkvlo + ((size_t)(b * 256 + qt * 128)) * 1536 + 1024 + h * 64 };
        ushort* vdsts[2] = { VThi, VTlo };
        #pragma unroll
        for (int pass = 0; pass < 2; ++pass) {
            __syncthreads();
            if (tid < 128) {
                const ushort* p = vsrcs[pass] + (size_t)tid * 1536;
                #pragma unroll
                for (int i = 0; i < 8; ++i) {
                    ushortx8 vv = *(const ushortx8*)(p + i * 8);
                    #pragma unroll
                    for (int j = 0; j < 8; ++j) T[(i * 8 + j) * TP + tid] = vv[j];
                }
            }
            __syncthreads();
            {
                const int dh = tid >> 2;
                const int kseg = (tid & 3) * 32;
                ushort* op = vdsts[pass] + ((size_t)bh * 64 + dh) * 256 + qt * 128 + kseg;
                #pragma unroll
                for (int i = 0; i < 4; ++i) {
                    ushortx8 vv;
                    #pragma unroll
                    for (int j = 0; j < 8; ++j) vv[j] = T[dh * TP + kseg + i * 8 + j];
                    *(ushortx8*)(op + i * 8) = vv;
                }
            }
        }
    }
}

// ---------------------------------------------------------------------------
// Batched PV: O[q][dh] = P[q][:] . V[:, dh] (bf16x3), O written split hi/lo.
// ---------------------------------------------------------------------------
__global__ __launch_bounds__(256)
void pv_gemm(const ushort* __restrict__ Phi, const ushort* __restrict__ Plo,
             const ushort* __restrict__ VThi, const ushort* __restrict__ VTlo,
             ushort* __restrict__ obhi, ushort* __restrict__ oblo, int t0)
{
    __shared__ __align__(16) ushort Als[2][2][128*32];
    __shared__ __align__(16) ushort Bls[2][2][64*32];
    const int tid = threadIdx.x, wave = tid >> 6, lane = tid & 63;
    const int swz = xcd_swz(blockIdx.y * 2 + blockIdx.x, 256);
    const int bh = swz >> 1, qt = swz & 1;
    const ushort* Ah = Phi + ((size_t)bh * 256 + qt * 128) * 256;
    const ushort* Al = Plo + ((size_t)bh * 256 + qt * 128) * 256;
    const ushort* Bh = VThi + (size_t)bh * 64 * 256;
    const ushort* Bl = VTlo + (size_t)bh * 64 * 256;

    f32x4 acc[2][4];
    #pragma unroll
    for (int m = 0; m < 2; ++m)
        #pragma unroll
        for (int n = 0; n < 4; ++n)
            acc[m][n] = (f32x4){0.f, 0.f, 0.f, 0.f};

    auto stage = [&](int buf, int kk) {
        #pragma unroll
        for (int i = 0; i < 2; ++i) {
            const int rbase = wave * 32 + i * 16;
            const int row   = rbase + (lane >> 2);
            const int slot  = (lane & 3) ^ ((row >> 1) & 3);
            GLDS(Ah + (size_t)row * 256 + kk + slot * 8, &Als[buf][0][rbase * 32]);
            GLDS(Al + (size_t)row * 256 + kk + slot * 8, &Als[buf][1][rbase * 32]);
        }
        const int rbase2 = wave * 16;
        const int row2   = rbase2 + (lane >> 2);
        const int slot2  = (lane & 3) ^ ((row2 >> 1) & 3);
        GLDS(Bh + (size_t)row2 * 256 + kk + slot2 * 8, &Bls[buf][0][rbase2 * 32]);
        GLDS(Bl + (size_t)row2 * 256 + kk + slot2 * 8, &Bls[buf][1][rbase2 * 32]);
    };

    stage(0, 0);
    for (int t = 0; t < 8; ++t) {
        const int buf = t & 1;
        __syncthreads();
        if (t < 7) stage(buf ^ 1, (t + 1) << 5);
        const int chunk = lane >> 4;
        bf16x8 afh[2], afl[2], bfh[4], bfl[4];
        #pragma unroll
        for (int m = 0; m < 2; ++m) {
            const int row = wave * 32 + m * 16 + (lane & 15);
            const int sl  = chunk ^ ((row >> 1) & 3);
            afh[m] = *(const bf16x8*)(&Als[buf][0][row * 32 + sl * 8]);
            afl[m] = *(const bf16x8*)(&Als[buf][1][row * 32 + sl * 8]);
        }
        #pragma unroll
        for (int n = 0; n < 4; ++n) {
            const int row = n * 16 + (lane & 15);
            const int sl  = chunk ^ ((row >> 1) & 3);
            bfh[n] = *(const bf16x8*)(&Bls[buf][0][row * 32 + sl * 8]);
            bfl[n] = *(const bf16x8*)(&Bls[buf][1][row * 32 + sl * 8]);
        }
        #pragma unroll
        for (int m = 0; m < 2; ++m)
            #pragma unroll
            for (int n = 0; n < 4; ++n) {
                acc[m][n] = __builtin_amdgcn_mfma_f32_16x16x32_bf16(afh[m], bfh[n], acc[m][n], 0, 0, 0);
                acc[m][n] = __builtin_amdgcn_mfma_f32_16x16x32_bf16(afh[m], bfl[n], acc[m][n], 0, 0, 0);
                acc[m][n] = __builtin_amdgcn_mfma_f32_16x16x32_bf16(afl[m], bfh[n], acc[m][n], 0, 0, 0);
            }
        __syncthreads();
    }

    const int b = bh >> 3, h = bh & 7;
    const int col_l = lane & 15;
    #pragma unroll
    for (int m = 0; m < 2; ++m)
        #pragma unroll
        for (int j = 0; j < 4; ++j) {
            const int q = qt * 128 + wave * 32 + m * 16 + (lane >> 4) * 4 + j;
            const size_t token = (size_t)t0 + (size_t)b * 256 + q;
            #pragma unroll
            for (int n = 0; n < 4; ++n) {
                const int col = h * 64 + n * 16 + col_l;
                float x = acc[m][n][j];
                ushort hb = bf16_rn(x);
                obhi[token * 512 + col] = hb;
                oblo[token * 512 + col] = bf16_rn(x - bf16_f32(hb));
            }
        }
}

// ---------------------------------------------------------------------------
// f32 GEMM (embedding only, K=32) with fused bf16 hi/lo split output.
// ---------------------------------------------------------------------------
__global__ __launch_bounds__(256)
void gemm_f32(const float* __restrict__ A, const float* __restrict__ W,
              const float* __restrict__ bias, float* __restrict__ Cc,
              ushort* __restrict__ Chi, ushort* __restrict__ Clo,
              int M, int N, int K)
{
    __shared__ float As[16][68];
    __shared__ float Bs[16][64];
    const int tid = threadIdx.x;
    const int tx = tid & 15, ty = tid >> 4;
    const int m0 = blockIdx.y << 6, n0 = blockIdx.x << 6;
    const int arow = tid >> 2, ak4 = (tid & 3) << 2;
    const int brow = tid >> 4, bc4 = (tid & 15) << 2;
    float acc[4][4] = {};
    const float* aptr = A + (size_t)(m0 + arow) * K + ak4;
    const float* bptr = W + (size_t)brow * N + n0 + bc4;
    for (int k0 = 0; k0 < K; k0 += 16) {
        float4 av = *(const float4*)(aptr + k0);
        float4 bv = *(const float4*)(bptr + (size_t)k0 * N);
        __syncthreads();
        As[ak4+0][arow] = av.x; As[ak4+1][arow] = av.y;
        As[ak4+2][arow] = av.z; As[ak4+3][arow] = av.w;
        *(float4*)&Bs[brow][bc4] = bv;
        __syncthreads();
        #pragma unroll
        for (int kk = 0; kk < 16; ++kk) {
            float4 a = *(const float4*)&As[kk][ty << 2];
            float4 b = *(const float4*)&Bs[kk][tx << 2];
            float ar[4] = {a.x,a.y,a.z,a.w};
            float br[4] = {b.x,b.y,b.z,b.w};
            #pragma unroll
            for (int i = 0; i < 4; ++i)
                #pragma unroll
                for (int j = 0; j < 4; ++j)
                    acc[i][j] = fmaf(ar[i], br[j], acc[i][j]);
        }
    }
    float4 bb = *(const float4*)(bias + n0 + (tx << 2));
    #pragma unroll
    for (int i = 0; i < 4; ++i) {
        int m = m0 + (ty << 2) + i;
        float o[4];
        o[0] = acc[i][0] + bb.x; o[1] = acc[i][1] + bb.y;
        o[2] = acc[i][2] + bb.z; o[3] = acc[i][3] + bb.w;
        ushort4 hh, ll;
        hh.x = bf16_rn(o[0]); ll.x = bf16_rn(o[0] - bf16_f32(hh.x));
        hh.y = bf16_rn(o[1]); ll.y = bf16_rn(o[1] - bf16_f32(hh.y));
        hh.z = bf16_rn(o[2]); ll.z = bf16_rn(o[2] - bf16_f32(hh.z));
        hh.w = bf16_rn(o[3]); ll.w = bf16_rn(o[3] - bf16_f32(hh.w));
        const size_t base = (size_t)m * N + n0 + (tx << 2);
        *(float4*)(Cc + base) = (float4){o[0],o[1],o[2],o[3]};
        *(ushort4*)(Chi + base) = hh;
        *(ushort4*)(Clo + base) = ll;
    }
}

// ---------------------------------------------------------------------------
// Per-layer weight prep: all 6 transposes + qkv-bias concat in ONE dispatch.
// ---------------------------------------------------------------------------
__global__ __launch_bounds__(256)
void prep_layer(const float* __restrict__ Wq, const float* __restrict__ Wk,
                const float* __restrict__ Wv, const float* __restrict__ Wo,
                const float* __restrict__ W1, const float* __restrict__ W2,
                const float* __restrict__ bq, const float* __restrict__ bk,
                const float* __restrict__ bv,
                ushort* __restrict__ WTQKV_HI, ushort* __restrict__ WTQKV_LO,
                ushort* __restrict__ WTO_HI, ushort* __restrict__ WTO_LO,
                ushort* __restrict__ WT1_HI, ushort* __restrict__ WT1_LO,
                ushort* __restrict__ WT2_HI, ushort* __restrict__ WT2_LO,
                float* __restrict__ biasqkv)
{
    __shared__ float T[64][65];
    const int blk = blockIdx.x;
    const int tid = threadIdx.x;
    if (blk >= 768) {
        int i = (blk - 768) * 256 + tid;
        biasqkv[i] = (i < 512) ? bq[i] : (i < 1024 ? bk[i - 512] : bv[i - 1024]);
        return;
    }
    const float* W; ushort* Thi; ushort* Tlo; int K, N, bx, by;
    if (blk < 192) {
        const int wsel = blk / 64, idx = blk % 64;
        W = (wsel == 0) ? Wq : ((wsel == 1) ? Wk : Wv);
        Thi = WTQKV_HI + (size_t)wsel * 512 * 512;
        Tlo = WTQKV_LO + (size_t)wsel * 512 * 512;
        K = 512; N = 512; bx = idx % 8; by = idx / 8;
    } else if (blk < 256) {
        const int idx = blk - 192;
        W = Wo; Thi = WTO_HI; Tlo = WTO_LO;
        K = 512; N = 512; bx = idx % 8; by = idx / 8;
    } else if (blk < 512) {
        const int idx = blk - 256;
        W = W1; Thi = WT1_HI; Tlo = WT1_LO;
        K = 512; N = 2048; bx = idx % 32; by = idx / 32;
    } else {
        const int idx = blk - 512;
        W = W2; Thi = WT2_HI; Tlo = WT2_LO;
        K = 2048; N = 512; bx = idx % 8; by = idx / 8;
    }
    const int k0 = by << 6, n0 = bx << 6;
    #pragma unroll
    for (int i = 0; i < 16; ++i) {
        int idx = tid + i * 256;
        int kl = idx >> 6, nl = idx & 63;
        T[nl][kl] = W[(size_t)(k0 + kl) * N + n0 + nl];
    }
    __syncthreads();
    #pragma unroll
    for (int i = 0; i < 16; ++i) {
        int idx = tid + i * 256;
        int nl = idx >> 6, kl = idx & 63;
        float x = T[nl][kl];
        ushort hb = bf16_rn(x);
        size_t o = (size_t)(n0 + nl) * K + k0 + kl;
        Thi[o] = hb;
        Tlo[o] = bf16_rn(x - bf16_f32(hb));
    }
}

// ---------------------------------------------------------------------------
// Head-weight prep: e1/e2/d1/d2 transposes in ONE 64-block dispatch.
// ---------------------------------------------------------------------------
__global__ __launch_bounds__(256)
void prep_heads(const float* __restrict__ e1_w, const float* __restrict__ e2_w,
                const float* __restrict__ d1_w, const float* __restrict__ d2_w,
                ushort* __restrict__ E1H, ushort* __restrict__ E1L,
                ushort* __restrict__ E2H, ushort* __restrict__ E2L,
                ushort* __restrict__ D1H, ushort* __restrict__ D1L,
                ushort* __restrict__ D2H, ushort* __restrict__ D2L)
{
    __shared__ float T[64][65];
    const int blk = blockIdx.x, tid = threadIdx.x;
    const int sel = blk >> 4, idx = blk & 15;
    const float* W; ushort* Thi; ushort* Tlo; int K, N, bx, by;
    if (sel == 0)      { W = e1_w; Thi = E1H; Tlo = E1L; K = 512; N = 128; bx = idx % 2; by = idx / 2; }
    else if (sel == 1) { W = e2_w; Thi = E2H; Tlo = E2L; K = 128; N = 512; bx = idx % 8; by = idx / 8; }
    else if (sel == 2) { W = d1_w; Thi = D1H; Tlo = D1L; K = 512; N = 128; bx = idx % 2; by = idx / 2; }
    else               { W = d2_w; Thi = D2H; Tlo = D2L; K = 128; N = 512; bx = idx % 8; by = idx / 8; }
    const int k0 = by << 6, n0 = bx << 6;
    #pragma unroll
    for (int i = 0; i < 16; ++i) {
        int ix = tid + i * 256;
        int kl = ix >> 6, nl = ix & 63;
        T[nl][kl] = W[(size_t)(k0 + kl) * N + n0 + nl];
    }
    __syncthreads();
    #pragma unroll
    for (int i = 0; i < 16; ++i) {
        int ix = tid + i * 256;
        int nl = ix >> 6, kl = ix & 63;
        float x = T[nl][kl];
        ushort hb = bf16_rn(x);
        size_t o = (size_t)(n0 + nl) * K + k0 + kl;
        Thi[o] = hb;
        Tlo[o] = bf16_rn(x - bf16_f32(hb));
    }
}

// ---------------------------------------------------------------------------
// residual + LN: 4 rows per 256-thread block (one wave per row).
// ---------------------------------------------------------------------------
__global__ __launch_bounds__(256)
void ln_res(float* __restrict__ h, const float* __restrict__ t,
            const float* __restrict__ sc, const float* __restrict__ bi,
            ushort* __restrict__ hhi, ushort* __restrict__ hlo)
{
    const int row = blockIdx.x * 4 + (threadIdx.x >> 6);
    const int lane = threadIdx.x & 63;
    const size_t off = (size_t)row * D_ + (size_t)lane * 8;
    float x[8];
    float4 a0 = *(const float4*)(h + off),  a1 = *(const float4*)(h + off + 4);
    float4 b0 = *(const float4*)(t + off),  b1 = *(const float4*)(t + off + 4);
    x[0]=a0.x+b0.x; x[1]=a0.y+b0.y; x[2]=a0.z+b0.z; x[3]=a0.w+b0.w;
    x[4]=a1.x+b1.x; x[5]=a1.y+b1.y; x[6]=a1.z+b1.z; x[7]=a1.w+b1.w;

    float s = 0.f;
    #pragma unroll
    for (int i = 0; i < 8; ++i) s += x[i];
    #pragma unroll
    for (int d = 1; d < 64; d <<= 1) s += __shfl_xor(s, d);
    float mean = s * (1.0f / 512.0f);

    float vsum = 0.f;
    #pragma unroll
    for (int i = 0; i < 8; ++i) { float dx = x[i] - mean; vsum += dx * dx; }
    #pragma unroll
    for (int d = 1; d < 64; d <<= 1) vsum += __shfl_xor(vsum, d);
    float den = sqrtf(vsum * (1.0f / 512.0f) + 1e-5f);

    float4 s0 = *(const float4*)(sc + lane*8), s1 = *(const float4*)(sc + lane*8 + 4);
    float4 c0 = *(const float4*)(bi + lane*8), c1 = *(const float4*)(bi + lane*8 + 4);
    float scv[8] = {s0.x,s0.y,s0.z,s0.w,s1.x,s1.y,s1.z,s1.w};
    float biv[8] = {c0.x,c0.y,c0.z,c0.w,c1.x,c1.y,c1.z,c1.w};
    float out[8];
    ushort hh[8], ll[8];
    #pragma unroll
    for (int i = 0; i < 8; ++i) {
        out[i] = (x[i] - mean) / den * scv[i] + biv[i];
        hh[i] = bf16_rn(out[i]);
        ll[i] = bf16_rn(out[i] - bf16_f32(hh[i]));
    }
    *(float4*)(h + off)     = (float4){out[0],out[1],out[2],out[3]};
    *(float4*)(h + off + 4) = (float4){out[4],out[5],out[6],out[7]};
    *(ushort4*)(hhi + off)     = (ushort4){hh[0],hh[1],hh[2],hh[3]};
    *(ushort4*)(hhi + off + 4) = (ushort4){hh[4],hh[5],hh[6],hh[7]};
    *(ushort4*)(hlo + off)     = (ushort4){ll[0],ll[1],ll[2],ll[3]};
    *(ushort4*)(hlo + off + 4) = (ushort4){ll[4],ll[5],ll[6],ll[7]};
}

// ---------------------------------------------------------------------------
// z -> d_out copy + sq[token] = sum(z^2), fused. 4 rows/block.
// ---------------------------------------------------------------------------
__global__ __launch_bounds__(256)
void zout_sq(const float* __restrict__ z, float* __restrict__ outz,
             float* __restrict__ sq)
{
#pragma clang fp contract(off)
    const int row = blockIdx.x * 4 + (threadIdx.x >> 6);
    const int lane = threadIdx.x & 63;
    const size_t off = (size_t)row * D_ + (size_t)lane * 8;
    const float* p = z + off;
    float4 a0 = *(const float4*)(p), a1 = *(const float4*)(p + 4);
    float vv[8] = {a0.x,a0.y,a0.z,a0.w,a1.x,a1.y,a1.z,a1.w};
    float* op = outz + off;
    #pragma unroll
    for (int i = 0; i < 8; ++i) op[i] = vv[i];
    float s = 0.f;
    #pragma unroll
    for (int i = 0; i < 8; ++i) { float t = vv[i] * vv[i]; s = s + t; }
    #pragma unroll
    for (int d = 1; d < 64; d <<= 1) s += __shfl_xor(s, d);
    if (lane == 0) sq[row] = s;
}

__global__ __launch_bounds__(256)
void gram_kernel(const float* __restrict__ z, float* __restrict__ gram)
{
    __shared__ float Ls[16][68];
    const int s = blockIdx.x;
    const int tid = threadIdx.x;
    const int tx = tid & 15, ty = tid >> 4;
    const int arow = tid >> 2, ak4 = (tid & 3) << 2;
    float acc[4][4] = {};
    const float* zp = z + ((size_t)arow * S_ + s) * D_ + ak4;
    for (int k0 = 0; k0 < D_; k0 += 16) {
        float4 av = *(const float4*)(zp + k0);
        __syncthreads();
        Ls[ak4+0][arow] = av.x; Ls[ak4+1][arow] = av.y;
        Ls[ak4+2][arow] = av.z; Ls[ak4+3][arow] = av.w;
        __syncthreads();
        #pragma unroll
        for (int kk = 0; kk < 16; ++kk) {
            float4 a = *(const float4*)&Ls[kk][ty << 2];
            float4 b = *(const float4*)&Ls[kk][tx << 2];
            float ar[4] = {a.x,a.y,a.z,a.w};
            float br[4] = {b.x,b.y,b.z,b.w};
            #pragma unroll
            for (int i = 0; i < 4; ++i)
                #pragma unroll
                for (int j = 0; j < 4; ++j)
                    acc[i][j] = fmaf(ar[i], br[j], acc[i][j]);
        }
    }
    #pragma unroll
    for (int i = 0; i < 4; ++i) {
        float4 o = {acc[i][0], acc[i][1], acc[i][2], acc[i][3]};
        *(float4*)(gram + ((size_t)s * 64 + (ty<<2) + i) * 64 + (tx<<2)) = o;
    }
}

__global__ __launch_bounds__(64)
void cluster_kernel(const float* __restrict__ gram, const float* __restrict__ sq,
                    const int* __restrict__ y, float* __restrict__ contrib,
                    int* __restrict__ assigned, float* __restrict__ out_assigned_f)
{
#pragma clang fp contract(off)
    __shared__ float G[64][65];
    __shared__ float sqs[64];
    const int s = blockIdx.x, b = threadIdx.x;
    for (int i = b; i < 4096; i += 64)
        G[i >> 6][i & 63] = gram[(size_t)s * 4096 + i];
    sqs[b] = sq[(size_t)b * S_ + s];
    __syncthreads();

    const float sqb = sqs[b];
    float dmin = INFINITY, dsum = 0.f;
    for (int c = 0; c < 64; ++c) {
        float d = sqb + sqs[c] - 2.0f * G[b][c];
        dmin = fminf(dmin, d);
        dsum = dsum + d;
    }
    float Z = 0.f;
    for (int c = 0; c < 64; ++c) {
        float d = sqb + sqs[c] - 2.0f * G[b][c];
        float e = expf(dmin - d);
        G[b][c] = e;
        Z = Z + e;
    }
    for (int c = 0; c < 64; ++c) G[b][c] = G[b][c] / Z;

    int knn[16];
    #pragma unroll
    for (int j = 0; j < 16; ++j) {
        float bp = -1.f; int bi2 = 0;
        for (int c = 0; c < 64; ++c) {
            float pv = G[b][c];
            if (pv > bp) { bp = pv; bi2 = c; }
        }
        knn[j] = bi2;
        G[b][bi2] = -1.f;
    }
    int cmatch = 0;
    #pragma unroll
    for (int j = 0; j < 16; ++j) cmatch += (knn[j] == j) ? 1 : 0;
    int lab[16];
    #pragma unroll
    for (int j = 0; j < 16; ++j) lab[j] = y[knn[j] * S_ + s];
    int bestc = -1, bestcls = 0;
    #pragma unroll
    for (int cls = 0; cls < 16; ++cls) {
        int cc = 0;
        #pragma unroll
        for (int j = 0; j < 16; ++j) cc += (lab[j] == cls) ? 1 : 0;
        if (cc > bestc) { bestc = cc; bestcls = cls; }
    }
    const int oi = s * 64 + b;
    contrib[oi] = dsum * (float)cmatch;
    assigned[oi] = bestcls;
    out_assigned_f[oi] = (float)bestcls;
}

__global__ __launch_bounds__(256)
void finalize_kernel(const float* __restrict__ contrib, const int* __restrict__ assigned,
                     const int* __restrict__ y, float* __restrict__ dout)
{
#pragma clang fp contract(off)
    __shared__ int cm[256];
    __shared__ float red[256];
    const int tid = threadIdx.x;
    cm[tid] = 0;
    float s = 0.f;
    for (int i = tid; i < NTOK; i += 256) s = s + contrib[i];
    red[tid] = s;
    __syncthreads();
    for (int i = tid; i < NTOK; i += 256)
        atomicAdd(&cm[assigned[i] * 16 + y[i]], 1);
    __syncthreads();
    for (int st = 128; st > 0; st >>= 1) {
        if (tid < st) red[tid] = red[tid] + red[tid + st];
        __syncthreads();
    }
    if (tid == 0) {
        dout[0] = red[0];
        float sij = 0.f, sa = 0.f, sb = 0.f;
        for (int i = 0; i < 256; ++i) {
            float mm = (float)cm[i];
            sij = sij + mm * (mm - 1.0f) * 0.5f;
        }
        for (int r = 0; r < 16; ++r) {
            int rs = 0;
            for (int c2 = 0; c2 < 16; ++c2) rs += cm[r * 16 + c2];
            float mm = (float)rs;
            sa = sa + mm * (mm - 1.0f) * 0.5f;
        }
        for (int c2 = 0; c2 < 16; ++c2) {
            int cs = 0;
            for (int r = 0; r < 16; ++r) cs += cm[r * 16 + c2];
            float mm = (float)cs;
            sb = sb + mm * (mm - 1.0f) * 0.5f;
        }
        float n = 16384.0f;
        float expv = sa * sb / (n * (n - 1.0f) * 0.5f);
        float mx = 0.5f * (sa + sb);
        dout[1] = (sij - expv) / (mx - expv);
    }
}

// ---------------------------------------------------------------------------
extern "C" void kernel_launch(void* const* d_in, const int* in_sizes, int n_in,
                              void* d_out, int out_size, void* d_ws, size_t ws_size,
                              hipStream_t stream)
{
    (void)in_sizes; (void)n_in; (void)out_size; (void)ws_size;
    const float* x     = (const float*)d_in[0];
    const float* W_emb = (const float*)d_in[1];
    const float* b_emb = (const float*)d_in[2];
    const float* Wq    = (const float*)d_in[3];
    const float* bq    = (const float*)d_in[4];
    const float* Wk    = (const float*)d_in[5];
    const float* bk    = (const float*)d_in[6];
    const float* Wv    = (const float*)d_in[7];
    const float* bv    = (const float*)d_in[8];
    const float* Wo    = (const float*)d_in[9];
    const float* bo    = (const float*)d_in[10];
    const float* ln1_s = (const float*)d_in[11];
    const float* ln1_b = (const float*)d_in[12];
    const float* W1    = (const float*)d_in[13];
    const float* b1    = (const float*)d_in[14];
    const float* W2    = (const float*)d_in[15];
    const float* b2    = (const float*)d_in[16];
    const float* ln2_s = (const float*)d_in[17];
    const float* ln2_b = (const float*)d_in[18];
    const float* e1_w  = (const float*)d_in[19];
    const float* e1_b  = (const float*)d_in[20];
    const float* e2_w  = (const float*)d_in[21];
    const float* e2_b  = (const float*)d_in[22];
    const float* d1_w  = (const float*)d_in[23];
    const float* d1_b  = (const float*)d_in[24];
    const float* d2_w  = (const float*)d_in[25];
    const float* d2_b  = (const float*)d_in[26];
    const int*   y     = (const int*)d_in[27];

    float* ws = (float*)d_ws;
    float*  h    = ws;                                   // 8388608
    ushort* hhi  = (ushort*)(ws + 8388608);
    ushort* hlo  = (ushort*)(ws + 12582912);
    float*  SCR  = ws + 16777216;                        // 20971520 slots scratch
    ushort* obhi = (ushort*)(ws + 37748736);
    ushort* oblo = (ushort*)(ws + 41943040);
    float*  wt   = ws + 46137344;
    ushort* WTQKV_HI = (ushort*)wt;
    ushort* WTQKV_LO = WTQKV_HI + 786432;
    ushort* WTO_HI   = WTQKV_LO + 786432;
    ushort* WTO_LO   = WTO_HI + 262144;
    ushort* WT1_HI   = WTO_LO + 262144;
    ushort* WT1_LO   = WT1_HI + 1048576;
    ushort* WT2_HI   = WT1_LO + 1048576;
    ushort* WT2_LO   = WT2_HI + 1048576;
    ushort* WE1_HI   = WT2_LO + 1048576;
    ushort* WE1_LO   = WE1_HI + 65536;
    ushort* WE2_HI   = WE1_LO + 65536;
    ushort* WE2_LO   = WE2_HI + 65536;
    ushort* WD1_HI   = WE2_LO + 65536;
    ushort* WD1_LO   = WD1_HI + 65536;
    ushort* WD2_HI   = WD1_LO + 65536;
    ushort* WD2_LO   = WD2_HI + 65536;
    float*  biasqkv  = ws + 49545216;

    // attention-phase overlays
    ushort* Phi_  = (ushort*)SCR;
    ushort* Plo_  = (ushort*)(SCR + 4194304);
    ushort* qkvhi = (ushort*)(SCR + 8388608);
    ushort* qkvlo = (ushort*)(SCR + 11534336);
    ushort* VThi  = (ushort*)(SCR + 14680064);
    ushort* VTlo  = (ushort*)(SCR + 15728640);
    // post-attention / FFN phase:
    float*  Of32  = SCR;
    ushort* f1hi  = (ushort*)SCR;
    ushort* f1lo  = (ushort*)(SCR + 8388608);
    float*  Xhalf = SCR + 16777216;
    // cluster phase:
    ushort* enchi = (ushort*)SCR;
    ushort* enclo = (ushort*)(SCR + 4194304);
    float*  z     = SCR + 8388608;
    float*  gram  = SCR + 16777216;
    float*  sqb_  = SCR + 17825792;
    float*  contrib = SCR + 17842176;
    int*    assigned = (int*)(SCR + 17858560);
    ushort* t1hi = obhi;
    ushort* t1lo = oblo;
    ushort* t2hi = obhi + 2097152;
    ushort* t2lo = oblo + 2097152;
    float*  dout = (float*)d_out;

    dim3 blk(256);
    auto gg = [](int M, int N) { return dim3(N >> 7, M >> 7); };

    prep_heads<<<dim3(64), blk, 0, stream>>>(e1_w, e2_w, d1_w, d2_w,
        WE1_HI, WE1_LO, WE2_HI, WE2_LO, WD1_HI, WD1_LO, WD2_HI, WD2_LO);

    gemm_f32<<<dim3(8, 256), blk, 0, stream>>>(x, W_emb, b_emb, h, hhi, hlo, NTOK, D_, IN_);

    for (int l = 0; l < L_; ++l) {
        prep_layer<<<dim3(774), blk, 0, stream>>>(
            Wq + (size_t)l*D_*D_, Wk + (size_t)l*D_*D_, Wv + (size_t)l*D_*D_,
            Wo + (size_t)l*D_*D_, W1 + (size_t)l*D_*DFF_, W2 + (size_t)l*DFF_*D_,
            bq + l*D_, bk + l*D_, bv + l*D_,
            WTQKV_HI, WTQKV_LO, WTO_HI, WTO_LO, WT1_HI, WT1_LO, WT2_HI, WT2_LO,
            biasqkv);

        for (int qtr = 0; qtr < 4; ++qtr) {
            const size_t hoff = (size_t)qtr * 4096 * 512;
            gemm3<2><<<gg(4096, 1536), blk, 0, stream>>>(
                hhi + hoff, hlo + hoff, WTQKV_HI, WTQKV_LO, biasqkv,
                nullptr, qkvhi, qkvlo, 4096, 1536, 512);
            qks_gemm<<<dim3(2, 128), blk, 0, stream>>>(qkvhi, qkvlo, Phi_, Plo_,
                                                       VThi, VTlo);
            pv_gemm<<<dim3(2, 128), blk, 0, stream>>>(Phi_, Plo_, VThi, VTlo,
                                                      obhi, oblo, qtr * 4096);
        }
        gemm3<0><<<gg(NTOK, 512), blk, 0, stream>>>(
            obhi, oblo, WTO_HI, WTO_LO, bo + l*D_,
            Of32, nullptr, nullptr, NTOK, 512, 512);
        ln_res<<<dim3(NTOK / 4), blk, 0, stream>>>(h, Of32, ln1_s + l*D_, ln1_b + l*D_, hhi, hlo);

        for (int half = 0; half < 2; ++half) {
            const size_t ro = (size_t)half * HALF_ * D_;
            gemm3<3><<<gg(HALF_, DFF_), blk, 0, stream>>>(
                hhi + ro, hlo + ro, WT1_HI, WT1_LO, b1 + l*DFF_,
                nullptr, f1hi, f1lo, HALF_, 2048, 512);
            gemm3<0><<<gg(HALF_, 512), blk, 0, stream>>>(
                f1hi, f1lo, WT2_HI, WT2_LO, b2 + l*D_,
                Xhalf, nullptr, nullptr, HALF_, 512, 2048);
            ln_res<<<dim3(HALF_ / 4), blk, 0, stream>>>(
                h + ro, Xhalf, ln2_s + l*D_, ln2_b + l*D_, hhi + ro, hlo + ro);
        }
    }

    gemm3_n128<<<dim3(256), blk, 0, stream>>>(
        hhi, hlo, WE1_HI, WE1_LO, e1_b, t1hi, t1lo, NTOK);
    gemm3<2><<<gg(NTOK, 512), blk, 0, stream>>>(
        t1hi, t1lo, WE2_HI, WE2_LO, e2_b, nullptr, enchi, enclo, NTOK, 512, 128);
    gemm3_n128<<<dim3(256), blk, 0, stream>>>(
        enchi, enclo, WD1_HI, WD1_LO, d1_b, t2hi, t2lo, NTOK);
    gemm3<0><<<gg(NTOK, 512), blk, 0, stream>>>(
        t2hi, t2lo, WD2_HI, WD2_LO, d2_b, z, nullptr, nullptr, NTOK, 512, 128);

    zout_sq<<<dim3(NTOK / 4), blk, 0, stream>>>(z, dout + 16386, sqb_);
    gram_kernel<<<dim3(S_), blk, 0, stream>>>(z, gram);
    cluster_kernel<<<dim3(S_), dim3(64), 0, stream>>>(gram, sqb_, y, contrib, assigned, dout + 2);
    finalize_kernel<<<dim3(1), blk, 0, stream>>>(contrib, assigned, y, dout);
}